// Round 6
// baseline (1890.074 us; speedup 1.0000x reference)
//
#include <hip/hip_runtime.h>
#include <cstdint>
#include <cstddef>
#include <math.h>

#pragma clang fp contract(off)

#define PRE_NMS    6000
#define POST_NMS   300
#define NMS_W      94          /* ceil(6000/64) */
#define NBUCKET    4096
#define CAP        8192
#define NMS_TH     0.7f

typedef unsigned int u32;
typedef unsigned long long u64;

// ---------------- K1a: coarse histogram on bits[31:20] ----------------
__global__ void k_hist1(const float* __restrict__ scores, int N, int total,
                        u32* __restrict__ hist) {
    int idx = blockIdx.x * blockDim.x + threadIdx.x;
    if (idx >= total) return;
    int b = idx / N;
    u32 bits = __float_as_uint(scores[(size_t)idx * 2 + 1]);
    atomicAdd(&hist[b * NBUCKET + (bits >> 20)], 1u);
}

// ---------------- K2a: coarse threshold bucket t1 + count strictly above ----------------
__global__ void k_thresh1(const u32* __restrict__ hist, u32* __restrict__ t1,
                          u32* __restrict__ above1) {
    int b = blockIdx.x;
    __shared__ u32 h[NBUCKET];
    __shared__ u32 part[256];
    for (int t = threadIdx.x; t < NBUCKET; t += blockDim.x) h[t] = hist[b * NBUCKET + t];
    __syncthreads();
    if (threadIdx.x < 256) {
        u32 s = 0;
        for (int j = 0; j < 16; ++j) s += h[threadIdx.x * 16 + j];
        part[threadIdx.x] = s;
    }
    __syncthreads();
    if (threadIdx.x == 0) {
        u32 acc = 0;
        int c;
        for (c = 255; c >= 0; --c) {
            if (acc + part[c] >= PRE_NMS) break;
            acc += part[c];
        }
        int t;
        for (t = c * 16 + 15; ; --t) {
            if (acc + h[t] >= PRE_NMS) break;
            acc += h[t];
        }
        t1[b] = (u32)t;
        above1[b] = acc;     // count with bucket strictly greater than t
    }
}

// ---------------- K1b: fine histogram of bucket-t1 elements on bits[19:8] ----------------
__global__ void k_hist2(const float* __restrict__ scores, int N, int total,
                        const u32* __restrict__ t1, u32* __restrict__ hist2) {
    int idx = blockIdx.x * blockDim.x + threadIdx.x;
    if (idx >= total) return;
    int b = idx / N;
    u32 bits = __float_as_uint(scores[(size_t)idx * 2 + 1]);
    if ((bits >> 20) == t1[b])
        atomicAdd(&hist2[b * NBUCKET + ((bits >> 8) & 0xFFFu)], 1u);
}

// ---------------- K2b: fine threshold t2 within bucket t1 ----------------
__global__ void k_thresh2(const u32* __restrict__ hist2, const u32* __restrict__ above1,
                          u32* __restrict__ t2) {
    int b = blockIdx.x;
    __shared__ u32 h[NBUCKET];
    __shared__ u32 part[256];
    for (int t = threadIdx.x; t < NBUCKET; t += blockDim.x) h[t] = hist2[b * NBUCKET + t];
    __syncthreads();
    if (threadIdx.x < 256) {
        u32 s = 0;
        for (int j = 0; j < 16; ++j) s += h[threadIdx.x * 16 + j];
        part[threadIdx.x] = s;
    }
    __syncthreads();
    if (threadIdx.x == 0) {
        u32 need = PRE_NMS - above1[b];   // >0 by construction of t1
        u32 acc = 0;
        int c;
        for (c = 255; c >= 0; --c) {
            if (acc + part[c] >= need) break;
            acc += part[c];
        }
        int t;
        for (t = c * 16 + 15; ; --t) {
            if (acc + h[t] >= need) break;
            acc += h[t];
        }
        t2[b] = (u32)t;
    }
}

// ---------------- K3: gather candidate keys ----------------
__global__ void k_gather(const float* __restrict__ scores, int N, int total,
                         const u32* __restrict__ t1, const u32* __restrict__ t2,
                         u32* __restrict__ cnt, u64* __restrict__ keys) {
    int idx = blockIdx.x * blockDim.x + threadIdx.x;
    if (idx >= total) return;
    int b = idx / N;
    int i = idx - b * N;
    u32 bits = __float_as_uint(scores[(size_t)idx * 2 + 1]);
    u32 bk = bits >> 20;
    u32 t1v = t1[b];
    bool take = (bk > t1v) || (bk == t1v && ((bits >> 8) & 0xFFFu) >= t2[b]);
    if (take) {
        u32 pos = atomicAdd(&cnt[b], 1u);
        if (pos < CAP)
            keys[(size_t)b * CAP + pos] = ((u64)bits << 32) | (u32)(~i);
    }
}

// ---------------- K4: bitonic sort 8192 keys, write top-6000 indices ----------------
__global__ __launch_bounds__(1024) void k_sort(const u64* __restrict__ keys,
                                               const u32* __restrict__ cnt,
                                               u32* __restrict__ sel) {
    int b = blockIdx.x;
    __shared__ u64 a[CAP];
    u32 c = cnt[b];
    if (c > CAP) c = CAP;
    for (int t = threadIdx.x; t < CAP; t += 1024)
        a[t] = (t < (int)c) ? keys[(size_t)b * CAP + t] : 0ull;
    __syncthreads();
    for (int k = 2; k <= CAP; k <<= 1) {
        for (int j = k >> 1; j > 0; j >>= 1) {
            for (int t = threadIdx.x; t < CAP / 2; t += 1024) {
                int i = ((t & ~(j - 1)) << 1) | (t & (j - 1));
                int p = i | j;
                u64 x = a[i], y = a[p];
                bool up = (i & k) == 0;
                bool sw = up ? (x < y) : (x > y);   // descending sort
                if (sw) { a[i] = y; a[p] = x; }
            }
            __syncthreads();
        }
    }
    for (int r = threadIdx.x; r < PRE_NMS; r += 1024)
        sel[b * PRE_NMS + r] = ~(u32)(a[r]);
}

// ---------------- K5: decode + clip selected boxes (left & right) ----------------
__global__ void k_decode(const float* __restrict__ deltas, const float* __restrict__ anchors,
                         const float* __restrict__ im_info, const u32* __restrict__ sel,
                         int N, int total, float* __restrict__ boxes) {
#pragma clang fp contract(off)
    int idx = blockIdx.x * blockDim.x + threadIdx.x;
    if (idx >= total) return;
    int b = idx / PRE_NMS;
    int r = idx - b * PRE_NMS;
    u32 i = sel[idx];
    float4 a = ((const float4*)anchors)[i];
    const float* d = deltas + ((size_t)b * N + i) * 6;
    float d0 = d[0], d1 = d[1], d2 = d[2], d3 = d[3], d4 = d[4], d5 = d[5];
    float w  = a.z - a.x + 1.0f;
    float h  = a.w - a.y + 1.0f;
    float cx = a.x + 0.5f * w;
    float cy = a.y + 0.5f * h;
    float Hm1 = im_info[b * 3 + 0] - 1.0f;
    float Wm1 = im_info[b * 3 + 1] - 1.0f;

    // correctly-rounded f32 exp via double (matches numpy's near-CR f32 exp)
    float e3 = (float)exp((double)d3);
    float e2 = (float)exp((double)d2);
    float e5 = (float)exp((double)d5);

    float pcy = d1 * h + cy;
    float ph  = e3 * h;
    float y1 = fminf(fmaxf(pcy - 0.5f * ph, 0.0f), Hm1);
    float y2 = fminf(fmaxf(pcy + 0.5f * ph, 0.0f), Hm1);

    {   // left: dx=d0, dw=d2
        float pcx = d0 * w + cx;
        float pw  = e2 * w;
        float x1 = fminf(fmaxf(pcx - 0.5f * pw, 0.0f), Wm1);
        float x2 = fminf(fmaxf(pcx + 0.5f * pw, 0.0f), Wm1);
        float* o = boxes + ((size_t)(b * 2 + 0) * PRE_NMS + r) * 4;
        o[0] = x1; o[1] = y1; o[2] = x2; o[3] = y2;
    }
    {   // right: dx=d4, dw=d5
        float pcx = d4 * w + cx;
        float pw  = e5 * w;
        float x1 = fminf(fmaxf(pcx - 0.5f * pw, 0.0f), Wm1);
        float x2 = fminf(fmaxf(pcx + 0.5f * pw, 0.0f), Wm1);
        float* o = boxes + ((size_t)(b * 2 + 1) * PRE_NMS + r) * 4;
        o[0] = x1; o[1] = y1; o[2] = x2; o[3] = y2;
    }
}

// ---------------- K6: pairwise IoU bitmask (upper triangle, j>i) ----------------
__global__ void k_mask(const float* __restrict__ boxes, u64* __restrict__ masks) {
#pragma clang fp contract(off)
    int z = blockIdx.z;
    const float* bx = boxes + (size_t)z * PRE_NMS * 4;
    u64* m = masks + (size_t)z * PRE_NMS * NMS_W;
    int rowStart = blockIdx.y * 64;
    int colStart = blockIdx.x * 64;
    int row = rowStart + threadIdx.x;
    if (blockIdx.x < blockIdx.y) {           // all cols < row: zero word
        if (row < PRE_NMS) m[(size_t)row * NMS_W + blockIdx.x] = 0ull;
        return;
    }
    __shared__ float4 cb[64];
    int col0 = colStart + threadIdx.x;
    cb[threadIdx.x] = (col0 < PRE_NMS) ? ((const float4*)bx)[col0] : make_float4(0.f, 0.f, 0.f, 0.f);
    __syncthreads();
    if (row >= PRE_NMS) return;
    float4 rb = ((const float4*)bx)[row];
    float rA = (rb.z - rb.x + 1.0f) * (rb.w - rb.y + 1.0f);
    u64 word = 0;
    #pragma unroll 4
    for (int c = 0; c < 64; ++c) {
        int col = colStart + c;
        if (col <= row || col >= PRE_NMS) continue;
        float4 q = cb[c];
        float xx1 = fmaxf(rb.x, q.x);
        float yy1 = fmaxf(rb.y, q.y);
        float xx2 = fminf(rb.z, q.z);
        float yy2 = fminf(rb.w, q.w);
        float iw = fmaxf(xx2 - xx1 + 1.0f, 0.0f);
        float ih = fmaxf(yy2 - yy1 + 1.0f, 0.0f);
        float inter = iw * ih;
        float qA = (q.z - q.x + 1.0f) * (q.w - q.y + 1.0f);
        float iou = inter / (rA + qA - inter);
        if (iou > NMS_TH) word |= (1ull << c);
    }
    m[(size_t)row * NMS_W + blockIdx.x] = word;
}

// ---------------- K7: sequential greedy scan (one wave per image-side) ----------------
#define SCAN_D 16
#define PREF(B0_, B1_, Bd_, CH)                                                     \
    if ((CH) < nC) {                                                                \
        _Pragma("unroll")                                                           \
        for (int t = 0; t < SCAN_D; ++t) {                                          \
            int i = (CH) * SCAN_D + t;                                              \
            size_t base = (size_t)i * NMS_W;                                        \
            B0_[t] = m[base + lane];                                                \
            B1_[t] = has1 ? m[base + 64 + lane] : 0ull;                             \
            Bd_[t] = m[base + (i >> 6)];                                            \
        }                                                                           \
    }
#define PROC(B0_, B1_, Bd_, CH)                                                     \
    {                                                                               \
        _Pragma("unroll")                                                           \
        for (int t = 0; t < SCAN_D; ++t) {                                          \
            int i = (CH) * SCAN_D + t;                                              \
            if ((i & 63) == 0) {                                                    \
                int wi = i >> 6;                                                    \
                cur = (wi < 64) ? __shfl(sup0, wi) : __shfl(sup1, wi - 64);         \
            }                                                                       \
            if (!((cur >> (i & 63)) & 1ull)) {                                      \
                sup0 |= B0_[t]; sup1 |= B1_[t]; cur |= Bd_[t];                      \
            }                                                                       \
        }                                                                           \
    }

__global__ __launch_bounds__(64) void k_scan(const u64* __restrict__ masks,
                                             u64* __restrict__ keep) {
    int z = blockIdx.x;
    const u64* m = masks + (size_t)z * PRE_NMS * NMS_W;
    int lane = threadIdx.x;
    bool has1 = (lane + 64) < NMS_W;
    u64 sup0 = 0, sup1 = 0, cur = 0;
    u64 A0[SCAN_D], A1[SCAN_D], Ad[SCAN_D];
    u64 B0[SCAN_D], B1[SCAN_D], Bd[SCAN_D];
    u64 C0[SCAN_D], C1[SCAN_D], Cd[SCAN_D];
    const int nC = PRE_NMS / SCAN_D;   // 375, divisible by 3
    PREF(A0, A1, Ad, 0)
    PREF(B0, B1, Bd, 1)
    for (int c = 0; c < nC; c += 3) {
        PREF(C0, C1, Cd, c + 2)
        PROC(A0, A1, Ad, c)
        PREF(A0, A1, Ad, c + 3)
        PROC(B0, B1, Bd, c + 1)
        PREF(B0, B1, Bd, c + 4)
        PROC(C0, C1, Cd, c + 2)
    }
    keep[(size_t)z * NMS_W + lane] = ~sup0;
    if (has1) keep[(size_t)z * NMS_W + 64 + lane] = ~sup1;
}

// ---------------- K8: combine keeps, compact, write output ----------------
__global__ void k_final(const u64* __restrict__ keepw, const float* __restrict__ boxes,
                        float* __restrict__ out, int B) {
    int b = blockIdx.x;
    __shared__ u64 comb[NMS_W];
    __shared__ u32 pref[NMS_W + 1];
    int t = threadIdx.x;   // block = 128
    if (t < NMS_W) {
        u64 c = keepw[(size_t)(b * 2 + 0) * NMS_W + t] & keepw[(size_t)(b * 2 + 1) * NMS_W + t];
        if (t == NMS_W - 1) c &= (1ull << (PRE_NMS - 64 * (NMS_W - 1))) - 1ull;
        comb[t] = c;
    }
    __syncthreads();
    if (t == 0) {
        u32 acc = 0;
        for (int w = 0; w < NMS_W; ++w) { pref[w] = acc; acc += (u32)__popcll(comb[w]); }
        pref[NMS_W] = acc;
    }
    __syncthreads();
    u32 nk = pref[NMS_W];
    const float* bl = boxes + (size_t)(b * 2 + 0) * PRE_NMS * 4;
    const float* br = boxes + (size_t)(b * 2 + 1) * PRE_NMS * 4;
    float* outL = out + (size_t)b * POST_NMS * 5;
    float* outR = out + (size_t)B * POST_NMS * 5 + (size_t)b * POST_NMS * 5;
    if (t < NMS_W) {
        u64 c = comb[t];
        u32 r = pref[t];
        while (c) {
            int bit = __ffsll((long long)c) - 1;
            c &= c - 1;
            if (r < POST_NMS) {
                int i = t * 64 + bit;
                float4 L = ((const float4*)bl)[i];
                float4 R = ((const float4*)br)[i];
                outL[r * 5 + 0] = (float)b;
                outL[r * 5 + 1] = L.x; outL[r * 5 + 2] = L.y;
                outL[r * 5 + 3] = L.z; outL[r * 5 + 4] = L.w;
                outR[r * 5 + 0] = (float)b;
                outR[r * 5 + 1] = R.x; outR[r * 5 + 2] = R.y;
                outR[r * 5 + 3] = R.z; outR[r * 5 + 4] = R.w;
            }
            ++r;
        }
    }
    for (u32 r = nk + t; r < POST_NMS; r += blockDim.x) {
        outL[r * 5 + 0] = (float)b;
        outL[r * 5 + 1] = 0.f; outL[r * 5 + 2] = 0.f; outL[r * 5 + 3] = 0.f; outL[r * 5 + 4] = 0.f;
        outR[r * 5 + 0] = (float)b;
        outR[r * 5 + 1] = 0.f; outR[r * 5 + 2] = 0.f; outR[r * 5 + 3] = 0.f; outR[r * 5 + 4] = 0.f;
    }
}

extern "C" void kernel_launch(void* const* d_in, const int* in_sizes, int n_in,
                              void* d_out, int out_size, void* d_ws, size_t ws_size,
                              hipStream_t stream) {
    const float* scores  = (const float*)d_in[0];
    const float* deltas  = (const float*)d_in[1];
    const float* im_info = (const float*)d_in[2];
    const float* anchors = (const float*)d_in[3];
    int B = in_sizes[2] / 3;      // 2
    int N = in_sizes[3] / 4;      // 245520

    char* p = (char*)d_ws;
    auto alloc = [&](size_t bytes) -> char* {
        char* r = p;
        p += (bytes + 255) & ~(size_t)255;
        return r;
    };
    u32*  hist1 = (u32*) alloc((size_t)B * NBUCKET * 4);
    u32*  hist2 = (u32*) alloc((size_t)B * NBUCKET * 4);
    u32*  cnt   = (u32*) alloc((size_t)B * 4);
    u32*  t1    = (u32*) alloc((size_t)B * 4);
    u32*  t2    = (u32*) alloc((size_t)B * 4);
    u32*  above1= (u32*) alloc((size_t)B * 4);
    u64*  keys  = (u64*) alloc((size_t)B * CAP * 8);
    u32*  sel   = (u32*) alloc((size_t)B * PRE_NMS * 4);
    float* boxes = (float*)alloc((size_t)B * 2 * PRE_NMS * 4 * 4);
    u64*  keep  = (u64*) alloc((size_t)B * 2 * NMS_W * 8);
    u64*  masks = (u64*) alloc((size_t)B * 2 * PRE_NMS * NMS_W * 8);

    hipMemsetAsync(hist1, 0, (size_t)B * NBUCKET * 4, stream);
    hipMemsetAsync(hist2, 0, (size_t)B * NBUCKET * 4, stream);
    hipMemsetAsync(cnt,   0, (size_t)B * 4, stream);

    int total = B * N;
    k_hist1  <<<(total + 255) / 256, 256, 0, stream>>>(scores, N, total, hist1);
    k_thresh1<<<B, 256, 0, stream>>>(hist1, t1, above1);
    k_hist2  <<<(total + 255) / 256, 256, 0, stream>>>(scores, N, total, t1, hist2);
    k_thresh2<<<B, 256, 0, stream>>>(hist2, above1, t2);
    k_gather <<<(total + 255) / 256, 256, 0, stream>>>(scores, N, total, t1, t2, cnt, keys);
    k_sort   <<<B, 1024, 0, stream>>>(keys, cnt, sel);
    int dt = B * PRE_NMS;
    k_decode <<<(dt + 255) / 256, 256, 0, stream>>>(deltas, anchors, im_info, sel, N, dt, boxes);
    dim3 mg(NMS_W, NMS_W, B * 2);
    k_mask   <<<mg, 64, 0, stream>>>(boxes, masks);
    k_scan   <<<B * 2, 64, 0, stream>>>(masks, keep);
    k_final  <<<B, 128, 0, stream>>>(keep, boxes, (float*)d_out, B);
}

// Round 7
// 1080.806 us; speedup vs baseline: 1.7488x; 1.7488x over previous
//
#include <hip/hip_runtime.h>
#include <cstdint>
#include <cstddef>
#include <math.h>

#pragma clang fp contract(off)

#define PRE_NMS    6000
#define POST_NMS   300
#define NMS_W      94          /* ceil(6000/64) */
#define NBUCKET    4096
#define CAP        8192
#define NMS_TH     0.7f

typedef unsigned int u32;
typedef unsigned long long u64;

// ---------------- K1a: coarse histogram on bits[31:20], LDS-privatized ----------------
__global__ void k_hist1(const float2* __restrict__ scores2, int N,
                        u32* __restrict__ hist) {
    int b = blockIdx.y;
    __shared__ u32 h[NBUCKET];
    for (int t = threadIdx.x; t < NBUCKET; t += blockDim.x) h[t] = 0;
    __syncthreads();
    for (int i = blockIdx.x * blockDim.x + threadIdx.x; i < N; i += gridDim.x * blockDim.x) {
        u32 bits = __float_as_uint(scores2[(size_t)b * N + i].y);
        atomicAdd(&h[bits >> 20], 1u);
    }
    __syncthreads();
    for (int t = threadIdx.x; t < NBUCKET; t += blockDim.x) {
        u32 v = h[t];
        if (v) atomicAdd(&hist[b * NBUCKET + t], v);
    }
}

// ---------------- K2a: coarse threshold bucket t1 + count strictly above ----------------
__global__ void k_thresh1(const u32* __restrict__ hist, u32* __restrict__ t1,
                          u32* __restrict__ above1) {
    int b = blockIdx.x;
    __shared__ u32 h[NBUCKET];
    __shared__ u32 part[256];
    for (int t = threadIdx.x; t < NBUCKET; t += blockDim.x) h[t] = hist[b * NBUCKET + t];
    __syncthreads();
    if (threadIdx.x < 256) {
        u32 s = 0;
        for (int j = 0; j < 16; ++j) s += h[threadIdx.x * 16 + j];
        part[threadIdx.x] = s;
    }
    __syncthreads();
    if (threadIdx.x == 0) {
        u32 acc = 0;
        int c;
        for (c = 255; c >= 0; --c) {
            if (acc + part[c] >= PRE_NMS) break;
            acc += part[c];
        }
        int t;
        for (t = c * 16 + 15; ; --t) {
            if (acc + h[t] >= PRE_NMS) break;
            acc += h[t];
        }
        t1[b] = (u32)t;
        above1[b] = acc;     // count with bucket strictly greater than t
    }
}

// ---------------- K1b: fine histogram of bucket-t1 elements on bits[19:8] ----------------
__global__ void k_hist2(const float2* __restrict__ scores2, int N,
                        const u32* __restrict__ t1, u32* __restrict__ hist2) {
    int b = blockIdx.y;
    u32 t1v = t1[b];
    __shared__ u32 h[NBUCKET];
    for (int t = threadIdx.x; t < NBUCKET; t += blockDim.x) h[t] = 0;
    __syncthreads();
    for (int i = blockIdx.x * blockDim.x + threadIdx.x; i < N; i += gridDim.x * blockDim.x) {
        u32 bits = __float_as_uint(scores2[(size_t)b * N + i].y);
        if ((bits >> 20) == t1v)
            atomicAdd(&h[(bits >> 8) & 0xFFFu], 1u);
    }
    __syncthreads();
    for (int t = threadIdx.x; t < NBUCKET; t += blockDim.x) {
        u32 v = h[t];
        if (v) atomicAdd(&hist2[b * NBUCKET + t], v);
    }
}

// ---------------- K2b: fine threshold t2 within bucket t1 ----------------
__global__ void k_thresh2(const u32* __restrict__ hist2, const u32* __restrict__ above1,
                          u32* __restrict__ t2) {
    int b = blockIdx.x;
    __shared__ u32 h[NBUCKET];
    __shared__ u32 part[256];
    for (int t = threadIdx.x; t < NBUCKET; t += blockDim.x) h[t] = hist2[b * NBUCKET + t];
    __syncthreads();
    if (threadIdx.x < 256) {
        u32 s = 0;
        for (int j = 0; j < 16; ++j) s += h[threadIdx.x * 16 + j];
        part[threadIdx.x] = s;
    }
    __syncthreads();
    if (threadIdx.x == 0) {
        u32 need = PRE_NMS - above1[b];   // >0 by construction of t1
        u32 acc = 0;
        int c;
        for (c = 255; c >= 0; --c) {
            if (acc + part[c] >= need) break;
            acc += part[c];
        }
        int t;
        for (t = c * 16 + 15; ; --t) {
            if (acc + h[t] >= need) break;
            acc += h[t];
        }
        t2[b] = (u32)t;
    }
}

// ---------------- K3: gather candidate keys ----------------
__global__ void k_gather(const float2* __restrict__ scores2, int N, int total,
                         const u32* __restrict__ t1, const u32* __restrict__ t2,
                         u32* __restrict__ cnt, u64* __restrict__ keys) {
    int idx = blockIdx.x * blockDim.x + threadIdx.x;
    if (idx >= total) return;
    int b = idx / N;
    int i = idx - b * N;
    u32 bits = __float_as_uint(scores2[idx].y);
    u32 bk = bits >> 20;
    u32 t1v = t1[b];
    bool take = (bk > t1v) || (bk == t1v && ((bits >> 8) & 0xFFFu) >= t2[b]);
    if (take) {
        u32 pos = atomicAdd(&cnt[b], 1u);
        if (pos < CAP)
            keys[(size_t)b * CAP + pos] = ((u64)bits << 32) | (u32)(~i);
    }
}

// ---------------- K4: bitonic sort 8192 keys, write top-6000 indices ----------------
__global__ __launch_bounds__(1024) void k_sort(const u64* __restrict__ keys,
                                               const u32* __restrict__ cnt,
                                               u32* __restrict__ sel) {
    int b = blockIdx.x;
    __shared__ u64 a[CAP];
    u32 c = cnt[b];
    if (c > CAP) c = CAP;
    for (int t = threadIdx.x; t < CAP; t += 1024)
        a[t] = (t < (int)c) ? keys[(size_t)b * CAP + t] : 0ull;
    __syncthreads();
    for (int k = 2; k <= CAP; k <<= 1) {
        for (int j = k >> 1; j > 0; j >>= 1) {
            for (int t = threadIdx.x; t < CAP / 2; t += 1024) {
                int i = ((t & ~(j - 1)) << 1) | (t & (j - 1));
                int p = i | j;
                u64 x = a[i], y = a[p];
                bool up = (i & k) == 0;
                bool sw = up ? (x < y) : (x > y);   // descending sort
                if (sw) { a[i] = y; a[p] = x; }
            }
            __syncthreads();
        }
    }
    for (int r = threadIdx.x; r < PRE_NMS; r += 1024)
        sel[b * PRE_NMS + r] = ~(u32)(a[r]);
}

// ---------------- K5: decode + clip selected boxes (left & right) ----------------
__global__ void k_decode(const float* __restrict__ deltas, const float* __restrict__ anchors,
                         const float* __restrict__ im_info, const u32* __restrict__ sel,
                         int N, int total, float* __restrict__ boxes) {
#pragma clang fp contract(off)
    int idx = blockIdx.x * blockDim.x + threadIdx.x;
    if (idx >= total) return;
    int b = idx / PRE_NMS;
    int r = idx - b * PRE_NMS;
    u32 i = sel[idx];
    float4 a = ((const float4*)anchors)[i];
    const float* d = deltas + ((size_t)b * N + i) * 6;
    float d0 = d[0], d1 = d[1], d2 = d[2], d3 = d[3], d4 = d[4], d5 = d[5];
    float w  = a.z - a.x + 1.0f;
    float h  = a.w - a.y + 1.0f;
    float cx = a.x + 0.5f * w;
    float cy = a.y + 0.5f * h;
    float Hm1 = im_info[b * 3 + 0] - 1.0f;
    float Wm1 = im_info[b * 3 + 1] - 1.0f;

    // correctly-rounded f32 exp via double (matches numpy's near-CR f32 exp)
    float e3 = (float)exp((double)d3);
    float e2 = (float)exp((double)d2);
    float e5 = (float)exp((double)d5);

    float pcy = d1 * h + cy;
    float ph  = e3 * h;
    float y1 = fminf(fmaxf(pcy - 0.5f * ph, 0.0f), Hm1);
    float y2 = fminf(fmaxf(pcy + 0.5f * ph, 0.0f), Hm1);

    {   // left: dx=d0, dw=d2
        float pcx = d0 * w + cx;
        float pw  = e2 * w;
        float x1 = fminf(fmaxf(pcx - 0.5f * pw, 0.0f), Wm1);
        float x2 = fminf(fmaxf(pcx + 0.5f * pw, 0.0f), Wm1);
        float* o = boxes + ((size_t)(b * 2 + 0) * PRE_NMS + r) * 4;
        o[0] = x1; o[1] = y1; o[2] = x2; o[3] = y2;
    }
    {   // right: dx=d4, dw=d5
        float pcx = d4 * w + cx;
        float pw  = e5 * w;
        float x1 = fminf(fmaxf(pcx - 0.5f * pw, 0.0f), Wm1);
        float x2 = fminf(fmaxf(pcx + 0.5f * pw, 0.0f), Wm1);
        float* o = boxes + ((size_t)(b * 2 + 1) * PRE_NMS + r) * 4;
        o[0] = x1; o[1] = y1; o[2] = x2; o[3] = y2;
    }
}

// ---------------- K6: pairwise IoU bitmask (upper triangle, j>i) ----------------
__global__ void k_mask(const float* __restrict__ boxes, u64* __restrict__ masks) {
#pragma clang fp contract(off)
    int z = blockIdx.z;
    const float* bx = boxes + (size_t)z * PRE_NMS * 4;
    u64* m = masks + (size_t)z * PRE_NMS * NMS_W;
    int rowStart = blockIdx.y * 64;
    int colStart = blockIdx.x * 64;
    int row = rowStart + threadIdx.x;
    if (blockIdx.x < blockIdx.y) {           // all cols < row: zero word
        if (row < PRE_NMS) m[(size_t)row * NMS_W + blockIdx.x] = 0ull;
        return;
    }
    __shared__ float4 cb[64];
    int col0 = colStart + threadIdx.x;
    cb[threadIdx.x] = (col0 < PRE_NMS) ? ((const float4*)bx)[col0] : make_float4(0.f, 0.f, 0.f, 0.f);
    __syncthreads();
    if (row >= PRE_NMS) return;
    float4 rb = ((const float4*)bx)[row];
    float rA = (rb.z - rb.x + 1.0f) * (rb.w - rb.y + 1.0f);
    u64 word = 0;
    #pragma unroll 4
    for (int c = 0; c < 64; ++c) {
        int col = colStart + c;
        if (col <= row || col >= PRE_NMS) continue;
        float4 q = cb[c];
        float xx1 = fmaxf(rb.x, q.x);
        float yy1 = fmaxf(rb.y, q.y);
        float xx2 = fminf(rb.z, q.z);
        float yy2 = fminf(rb.w, q.w);
        float iw = fmaxf(xx2 - xx1 + 1.0f, 0.0f);
        float ih = fmaxf(yy2 - yy1 + 1.0f, 0.0f);
        float inter = iw * ih;
        float qA = (q.z - q.x + 1.0f) * (q.w - q.y + 1.0f);
        float iou = inter / (rA + qA - inter);
        if (iou > NMS_TH) word |= (1ull << c);
    }
    m[(size_t)row * NMS_W + blockIdx.x] = word;
}

// ---------------- K7: sequential greedy scan (one wave per image-side) ----------------
// SCAN_D=8, triple-buffered: 3 bufs x (B0[8]+B1[8]+Bd[8]) = 72 u64 = 144 VGPR (fits; no scratch)
#define SCAN_D 8
#define PREF(B0_, B1_, Bd_, CH)                                                     \
    if ((CH) < nC) {                                                                \
        _Pragma("unroll")                                                           \
        for (int t = 0; t < SCAN_D; ++t) {                                          \
            int i = (CH) * SCAN_D + t;                                              \
            size_t base = (size_t)i * NMS_W;                                        \
            B0_[t] = m[base + lane];                                                \
            B1_[t] = has1 ? m[base + 64 + lane] : 0ull;                             \
            Bd_[t] = m[base + (i >> 6)];                                            \
        }                                                                           \
    }
#define PROC(B0_, B1_, Bd_, CH)                                                     \
    {                                                                               \
        _Pragma("unroll")                                                           \
        for (int t = 0; t < SCAN_D; ++t) {                                          \
            int i = (CH) * SCAN_D + t;                                              \
            if ((i & 63) == 0) {                                                    \
                int wi = i >> 6;                                                    \
                cur = (wi < 64) ? __shfl(sup0, wi) : __shfl(sup1, wi - 64);         \
            }                                                                       \
            if (!((cur >> (i & 63)) & 1ull)) {                                      \
                sup0 |= B0_[t]; sup1 |= B1_[t]; cur |= Bd_[t];                      \
            }                                                                       \
        }                                                                           \
    }

__global__ __launch_bounds__(64, 1) void k_scan(const u64* __restrict__ masks,
                                                u64* __restrict__ keep) {
    int z = blockIdx.x;
    const u64* m = masks + (size_t)z * PRE_NMS * NMS_W;
    int lane = threadIdx.x;
    bool has1 = (lane + 64) < NMS_W;
    u64 sup0 = 0, sup1 = 0, cur = 0;
    u64 A0[SCAN_D], A1[SCAN_D], Ad[SCAN_D];
    u64 B0[SCAN_D], B1[SCAN_D], Bd[SCAN_D];
    u64 C0[SCAN_D], C1[SCAN_D], Cd[SCAN_D];
    const int nC = PRE_NMS / SCAN_D;   // 750, divisible by 3
    PREF(A0, A1, Ad, 0)
    PREF(B0, B1, Bd, 1)
    for (int c = 0; c < nC; c += 3) {
        PREF(C0, C1, Cd, c + 2)
        PROC(A0, A1, Ad, c)
        PREF(A0, A1, Ad, c + 3)
        PROC(B0, B1, Bd, c + 1)
        PREF(B0, B1, Bd, c + 4)
        PROC(C0, C1, Cd, c + 2)
    }
    keep[(size_t)z * NMS_W + lane] = ~sup0;
    if (has1) keep[(size_t)z * NMS_W + 64 + lane] = ~sup1;
}

// ---------------- K8: combine keeps, compact, write output ----------------
__global__ void k_final(const u64* __restrict__ keepw, const float* __restrict__ boxes,
                        float* __restrict__ out, int B) {
    int b = blockIdx.x;
    __shared__ u64 comb[NMS_W];
    __shared__ u32 pref[NMS_W + 1];
    int t = threadIdx.x;   // block = 128
    if (t < NMS_W) {
        u64 c = keepw[(size_t)(b * 2 + 0) * NMS_W + t] & keepw[(size_t)(b * 2 + 1) * NMS_W + t];
        if (t == NMS_W - 1) c &= (1ull << (PRE_NMS - 64 * (NMS_W - 1))) - 1ull;
        comb[t] = c;
    }
    __syncthreads();
    if (t == 0) {
        u32 acc = 0;
        for (int w = 0; w < NMS_W; ++w) { pref[w] = acc; acc += (u32)__popcll(comb[w]); }
        pref[NMS_W] = acc;
    }
    __syncthreads();
    u32 nk = pref[NMS_W];
    const float* bl = boxes + (size_t)(b * 2 + 0) * PRE_NMS * 4;
    const float* br = boxes + (size_t)(b * 2 + 1) * PRE_NMS * 4;
    float* outL = out + (size_t)b * POST_NMS * 5;
    float* outR = out + (size_t)B * POST_NMS * 5 + (size_t)b * POST_NMS * 5;
    if (t < NMS_W) {
        u64 c = comb[t];
        u32 r = pref[t];
        while (c) {
            int bit = __ffsll((long long)c) - 1;
            c &= c - 1;
            if (r < POST_NMS) {
                int i = t * 64 + bit;
                float4 L = ((const float4*)bl)[i];
                float4 R = ((const float4*)br)[i];
                outL[r * 5 + 0] = (float)b;
                outL[r * 5 + 1] = L.x; outL[r * 5 + 2] = L.y;
                outL[r * 5 + 3] = L.z; outL[r * 5 + 4] = L.w;
                outR[r * 5 + 0] = (float)b;
                outR[r * 5 + 1] = R.x; outR[r * 5 + 2] = R.y;
                outR[r * 5 + 3] = R.z; outR[r * 5 + 4] = R.w;
            }
            ++r;
        }
    }
    for (u32 r = nk + t; r < POST_NMS; r += blockDim.x) {
        outL[r * 5 + 0] = (float)b;
        outL[r * 5 + 1] = 0.f; outL[r * 5 + 2] = 0.f; outL[r * 5 + 3] = 0.f; outL[r * 5 + 4] = 0.f;
        outR[r * 5 + 0] = (float)b;
        outR[r * 5 + 1] = 0.f; outR[r * 5 + 2] = 0.f; outR[r * 5 + 3] = 0.f; outR[r * 5 + 4] = 0.f;
    }
}

extern "C" void kernel_launch(void* const* d_in, const int* in_sizes, int n_in,
                              void* d_out, int out_size, void* d_ws, size_t ws_size,
                              hipStream_t stream) {
    const float* scores  = (const float*)d_in[0];
    const float* deltas  = (const float*)d_in[1];
    const float* im_info = (const float*)d_in[2];
    const float* anchors = (const float*)d_in[3];
    int B = in_sizes[2] / 3;      // 2
    int N = in_sizes[3] / 4;      // 245520

    char* p = (char*)d_ws;
    auto alloc = [&](size_t bytes) -> char* {
        char* r = p;
        p += (bytes + 255) & ~(size_t)255;
        return r;
    };
    u32*  hist1 = (u32*) alloc((size_t)B * NBUCKET * 4);
    u32*  hist2 = (u32*) alloc((size_t)B * NBUCKET * 4);
    u32*  cnt   = (u32*) alloc((size_t)B * 4);
    u32*  t1    = (u32*) alloc((size_t)B * 4);
    u32*  t2    = (u32*) alloc((size_t)B * 4);
    u32*  above1= (u32*) alloc((size_t)B * 4);
    u64*  keys  = (u64*) alloc((size_t)B * CAP * 8);
    u32*  sel   = (u32*) alloc((size_t)B * PRE_NMS * 4);
    float* boxes = (float*)alloc((size_t)B * 2 * PRE_NMS * 4 * 4);
    u64*  keep  = (u64*) alloc((size_t)B * 2 * NMS_W * 8);
    u64*  masks = (u64*) alloc((size_t)B * 2 * PRE_NMS * NMS_W * 8);

    hipMemsetAsync(hist1, 0, (size_t)B * NBUCKET * 4, stream);
    hipMemsetAsync(hist2, 0, (size_t)B * NBUCKET * 4, stream);
    hipMemsetAsync(cnt,   0, (size_t)B * 4, stream);

    int total = B * N;
    const float2* scores2 = (const float2*)scores;
    dim3 hg(128, B);
    k_hist1  <<<hg, 256, 0, stream>>>(scores2, N, hist1);
    k_thresh1<<<B, 256, 0, stream>>>(hist1, t1, above1);
    k_hist2  <<<hg, 256, 0, stream>>>(scores2, N, t1, hist2);
    k_thresh2<<<B, 256, 0, stream>>>(hist2, above1, t2);
    k_gather <<<(total + 255) / 256, 256, 0, stream>>>(scores2, N, total, t1, t2, cnt, keys);
    k_sort   <<<B, 1024, 0, stream>>>(keys, cnt, sel);
    int dt = B * PRE_NMS;
    k_decode <<<(dt + 255) / 256, 256, 0, stream>>>(deltas, anchors, im_info, sel, N, dt, boxes);
    dim3 mg(NMS_W, NMS_W, B * 2);
    k_mask   <<<mg, 64, 0, stream>>>(boxes, masks);
    k_scan   <<<B * 2, 64, 0, stream>>>(masks, keep);
    k_final  <<<B, 128, 0, stream>>>(keep, boxes, (float*)d_out, B);
}

// Round 8
// 762.695 us; speedup vs baseline: 2.4782x; 1.4171x over previous
//
#include <hip/hip_runtime.h>
#include <cstdint>
#include <cstddef>
#include <math.h>

#pragma clang fp contract(off)

#define PRE_NMS    6000
#define POST_NMS   300
#define NMS_W      94          /* ceil(6000/64) */
#define NBUCKET    4096
#define CAP        8192
#define NMS_TH     0.7f

typedef unsigned int u32;
typedef unsigned long long u64;

// ---------------- K1a: coarse histogram on bits[31:20], LDS-privatized ----------------
__global__ void k_hist1(const float2* __restrict__ scores2, int N,
                        u32* __restrict__ hist) {
    int b = blockIdx.y;
    __shared__ u32 h[NBUCKET];
    for (int t = threadIdx.x; t < NBUCKET; t += blockDim.x) h[t] = 0;
    __syncthreads();
    for (int i = blockIdx.x * blockDim.x + threadIdx.x; i < N; i += gridDim.x * blockDim.x) {
        u32 bits = __float_as_uint(scores2[(size_t)b * N + i].y);
        atomicAdd(&h[bits >> 20], 1u);
    }
    __syncthreads();
    for (int t = threadIdx.x; t < NBUCKET; t += blockDim.x) {
        u32 v = h[t];
        if (v) atomicAdd(&hist[b * NBUCKET + t], v);
    }
}

// ---------------- K2a: coarse threshold bucket t1 + count strictly above ----------------
__global__ void k_thresh1(const u32* __restrict__ hist, u32* __restrict__ t1,
                          u32* __restrict__ above1) {
    int b = blockIdx.x;
    __shared__ u32 h[NBUCKET];
    __shared__ u32 part[256];
    for (int t = threadIdx.x; t < NBUCKET; t += blockDim.x) h[t] = hist[b * NBUCKET + t];
    __syncthreads();
    if (threadIdx.x < 256) {
        u32 s = 0;
        for (int j = 0; j < 16; ++j) s += h[threadIdx.x * 16 + j];
        part[threadIdx.x] = s;
    }
    __syncthreads();
    if (threadIdx.x == 0) {
        u32 acc = 0;
        int c;
        for (c = 255; c >= 0; --c) {
            if (acc + part[c] >= PRE_NMS) break;
            acc += part[c];
        }
        int t;
        for (t = c * 16 + 15; ; --t) {
            if (acc + h[t] >= PRE_NMS) break;
            acc += h[t];
        }
        t1[b] = (u32)t;
        above1[b] = acc;     // count with bucket strictly greater than t
    }
}

// ---------------- K1b: fine histogram of bucket-t1 elements on bits[19:8] ----------------
__global__ void k_hist2(const float2* __restrict__ scores2, int N,
                        const u32* __restrict__ t1, u32* __restrict__ hist2) {
    int b = blockIdx.y;
    u32 t1v = t1[b];
    __shared__ u32 h[NBUCKET];
    for (int t = threadIdx.x; t < NBUCKET; t += blockDim.x) h[t] = 0;
    __syncthreads();
    for (int i = blockIdx.x * blockDim.x + threadIdx.x; i < N; i += gridDim.x * blockDim.x) {
        u32 bits = __float_as_uint(scores2[(size_t)b * N + i].y);
        if ((bits >> 20) == t1v)
            atomicAdd(&h[(bits >> 8) & 0xFFFu], 1u);
    }
    __syncthreads();
    for (int t = threadIdx.x; t < NBUCKET; t += blockDim.x) {
        u32 v = h[t];
        if (v) atomicAdd(&hist2[b * NBUCKET + t], v);
    }
}

// ---------------- K2b: fine threshold t2 within bucket t1 ----------------
__global__ void k_thresh2(const u32* __restrict__ hist2, const u32* __restrict__ above1,
                          u32* __restrict__ t2) {
    int b = blockIdx.x;
    __shared__ u32 h[NBUCKET];
    __shared__ u32 part[256];
    for (int t = threadIdx.x; t < NBUCKET; t += blockDim.x) h[t] = hist2[b * NBUCKET + t];
    __syncthreads();
    if (threadIdx.x < 256) {
        u32 s = 0;
        for (int j = 0; j < 16; ++j) s += h[threadIdx.x * 16 + j];
        part[threadIdx.x] = s;
    }
    __syncthreads();
    if (threadIdx.x == 0) {
        u32 need = PRE_NMS - above1[b];   // >0 by construction of t1
        u32 acc = 0;
        int c;
        for (c = 255; c >= 0; --c) {
            if (acc + part[c] >= need) break;
            acc += part[c];
        }
        int t;
        for (t = c * 16 + 15; ; --t) {
            if (acc + h[t] >= need) break;
            acc += h[t];
        }
        t2[b] = (u32)t;
    }
}

// ---------------- K3: gather candidate keys ----------------
__global__ void k_gather(const float2* __restrict__ scores2, int N, int total,
                         const u32* __restrict__ t1, const u32* __restrict__ t2,
                         u32* __restrict__ cnt, u64* __restrict__ keys) {
    int idx = blockIdx.x * blockDim.x + threadIdx.x;
    if (idx >= total) return;
    int b = idx / N;
    int i = idx - b * N;
    u32 bits = __float_as_uint(scores2[idx].y);
    u32 bk = bits >> 20;
    u32 t1v = t1[b];
    bool take = (bk > t1v) || (bk == t1v && ((bits >> 8) & 0xFFFu) >= t2[b]);
    if (take) {
        u32 pos = atomicAdd(&cnt[b], 1u);
        if (pos < CAP)
            keys[(size_t)b * CAP + pos] = ((u64)bits << 32) | (u32)(~i);
    }
}

// ---------------- K4: bitonic sort 8192 keys, write top-6000 indices ----------------
__global__ __launch_bounds__(1024) void k_sort(const u64* __restrict__ keys,
                                               const u32* __restrict__ cnt,
                                               u32* __restrict__ sel) {
    int b = blockIdx.x;
    __shared__ u64 a[CAP];
    u32 c = cnt[b];
    if (c > CAP) c = CAP;
    for (int t = threadIdx.x; t < CAP; t += 1024)
        a[t] = (t < (int)c) ? keys[(size_t)b * CAP + t] : 0ull;
    __syncthreads();
    for (int k = 2; k <= CAP; k <<= 1) {
        for (int j = k >> 1; j > 0; j >>= 1) {
            for (int t = threadIdx.x; t < CAP / 2; t += 1024) {
                int i = ((t & ~(j - 1)) << 1) | (t & (j - 1));
                int p = i | j;
                u64 x = a[i], y = a[p];
                bool up = (i & k) == 0;
                bool sw = up ? (x < y) : (x > y);   // descending sort
                if (sw) { a[i] = y; a[p] = x; }
            }
            __syncthreads();
        }
    }
    for (int r = threadIdx.x; r < PRE_NMS; r += 1024)
        sel[b * PRE_NMS + r] = ~(u32)(a[r]);
}

// ---------------- K5: decode + clip selected boxes (left & right) ----------------
__global__ void k_decode(const float* __restrict__ deltas, const float* __restrict__ anchors,
                         const float* __restrict__ im_info, const u32* __restrict__ sel,
                         int N, int total, float* __restrict__ boxes) {
#pragma clang fp contract(off)
    int idx = blockIdx.x * blockDim.x + threadIdx.x;
    if (idx >= total) return;
    int b = idx / PRE_NMS;
    int r = idx - b * PRE_NMS;
    u32 i = sel[idx];
    float4 a = ((const float4*)anchors)[i];
    const float* d = deltas + ((size_t)b * N + i) * 6;
    float d0 = d[0], d1 = d[1], d2 = d[2], d3 = d[3], d4 = d[4], d5 = d[5];
    float w  = a.z - a.x + 1.0f;
    float h  = a.w - a.y + 1.0f;
    float cx = a.x + 0.5f * w;
    float cy = a.y + 0.5f * h;
    float Hm1 = im_info[b * 3 + 0] - 1.0f;
    float Wm1 = im_info[b * 3 + 1] - 1.0f;

    // correctly-rounded f32 exp via double (matches numpy's near-CR f32 exp)
    float e3 = (float)exp((double)d3);
    float e2 = (float)exp((double)d2);
    float e5 = (float)exp((double)d5);

    float pcy = d1 * h + cy;
    float ph  = e3 * h;
    float y1 = fminf(fmaxf(pcy - 0.5f * ph, 0.0f), Hm1);
    float y2 = fminf(fmaxf(pcy + 0.5f * ph, 0.0f), Hm1);

    {   // left: dx=d0, dw=d2
        float pcx = d0 * w + cx;
        float pw  = e2 * w;
        float x1 = fminf(fmaxf(pcx - 0.5f * pw, 0.0f), Wm1);
        float x2 = fminf(fmaxf(pcx + 0.5f * pw, 0.0f), Wm1);
        float* o = boxes + ((size_t)(b * 2 + 0) * PRE_NMS + r) * 4;
        o[0] = x1; o[1] = y1; o[2] = x2; o[3] = y2;
    }
    {   // right: dx=d4, dw=d5
        float pcx = d4 * w + cx;
        float pw  = e5 * w;
        float x1 = fminf(fmaxf(pcx - 0.5f * pw, 0.0f), Wm1);
        float x2 = fminf(fmaxf(pcx + 0.5f * pw, 0.0f), Wm1);
        float* o = boxes + ((size_t)(b * 2 + 1) * PRE_NMS + r) * 4;
        o[0] = x1; o[1] = y1; o[2] = x2; o[3] = y2;
    }
}

// ---------------- K6: pairwise IoU bitmask (upper triangle, j>i) ----------------
__global__ void k_mask(const float* __restrict__ boxes, u64* __restrict__ masks) {
#pragma clang fp contract(off)
    int z = blockIdx.z;
    const float* bx = boxes + (size_t)z * PRE_NMS * 4;
    u64* m = masks + (size_t)z * PRE_NMS * NMS_W;
    int rowStart = blockIdx.y * 64;
    int colStart = blockIdx.x * 64;
    int row = rowStart + threadIdx.x;
    if (blockIdx.x < blockIdx.y) {           // all cols < row: zero word
        if (row < PRE_NMS) m[(size_t)row * NMS_W + blockIdx.x] = 0ull;
        return;
    }
    __shared__ float4 cb[64];
    int col0 = colStart + threadIdx.x;
    cb[threadIdx.x] = (col0 < PRE_NMS) ? ((const float4*)bx)[col0] : make_float4(0.f, 0.f, 0.f, 0.f);
    __syncthreads();
    if (row >= PRE_NMS) return;
    float4 rb = ((const float4*)bx)[row];
    float rA = (rb.z - rb.x + 1.0f) * (rb.w - rb.y + 1.0f);
    u64 word = 0;
    #pragma unroll 4
    for (int c = 0; c < 64; ++c) {
        int col = colStart + c;
        if (col <= row || col >= PRE_NMS) continue;
        float4 q = cb[c];
        float xx1 = fmaxf(rb.x, q.x);
        float yy1 = fmaxf(rb.y, q.y);
        float xx2 = fminf(rb.z, q.z);
        float yy2 = fminf(rb.w, q.w);
        float iw = fmaxf(xx2 - xx1 + 1.0f, 0.0f);
        float ih = fmaxf(yy2 - yy1 + 1.0f, 0.0f);
        float inter = iw * ih;
        float qA = (q.z - q.x + 1.0f) * (q.w - q.y + 1.0f);
        float iou = inter / (rA + qA - inter);
        if (iou > NMS_TH) word |= (1ull << c);
    }
    m[(size_t)row * NMS_W + blockIdx.x] = word;
}

// ---------------- K7: sequential greedy scan, producer-consumer through LDS ----------------
// 1 block (256 thr, 4 waves) per image-side. Per chunk of 32 rows:
//   all threads issue global loads for chunk c+1 -> regs;
//   wave 0 runs the serial chain on chunk c from LDS (batch ds_read -> unrolled reg arrays);
//   all threads ds_write chunk c+1; __syncthreads.
// Waves 1-3 stall on vmcnt during wave 0's PROC -> latency hidden by TLP, not reg pipelining.
#define SCAN_R 32
#define SCAN_CW (SCAN_R * NMS_W)            /* 3008 words per chunk */
#define SCAN_CP (SCAN_CW / 2)               /* 1504 u64-pairs */

__global__ __launch_bounds__(256, 1) void k_scan(const u64* __restrict__ masks,
                                                 u64* __restrict__ keep) {
    int z = blockIdx.x;
    const u64* m = masks + (size_t)z * PRE_NMS * NMS_W;
    __shared__ __align__(16) u64 buf[2][SCAN_CW];   // 48128 B
    int tid = threadIdx.x;
    int lane = tid & 63;
    int wave = tid >> 6;
    bool has1 = (lane + 64) < NMS_W;
    const int nC = (PRE_NMS + SCAN_R - 1) / SCAN_R;      // 188
    const size_t limPairs = (size_t)PRE_NMS * NMS_W / 2; // 282000

    // prologue: load chunk 0 into buf[0]
    {
        const ulonglong2* src = (const ulonglong2*)m;
        ulonglong2* dst = (ulonglong2*)buf[0];
        #pragma unroll
        for (int j = 0; j < 6; ++j) {
            int p = tid + j * 256;
            if (p < SCAN_CP) dst[p] = src[p];
        }
    }
    __syncthreads();

    u64 sup0 = 0, sup1 = 0, cur = 0;
    for (int c = 0; c < nC; ++c) {
        int bi = c & 1;
        // 1. issue global loads for chunk c+1 (held in regs across PROC)
        ulonglong2 r0[6];
        bool doload = (c + 1) < nC;
        if (doload) {
            size_t base = (size_t)(c + 1) * SCAN_CP;
            const ulonglong2* src = (const ulonglong2*)m;
            #pragma unroll
            for (int j = 0; j < 6; ++j) {
                int p = tid + j * 256;
                size_t gp = base + p;
                r0[j] = (p < SCAN_CP && gp < limPairs) ? src[gp]
                        : make_ulonglong2(0ull, 0ull);
            }
        }
        // 2. wave 0: serial chain on chunk c
        if (wave == 0) {
            u64 w0[SCAN_R], w1[SCAN_R], wd[SCAN_R];
            #pragma unroll
            for (int r = 0; r < SCAN_R; ++r) {
                int i = c * SCAN_R + r;
                w0[r] = buf[bi][r * NMS_W + lane];
                w1[r] = has1 ? buf[bi][r * NMS_W + 64 + lane] : 0ull;
                wd[r] = buf[bi][r * NMS_W + (i >> 6)];
            }
            __builtin_amdgcn_sched_barrier(0);
            #pragma unroll
            for (int r = 0; r < SCAN_R; ++r) {
                int i = c * SCAN_R + r;
                if ((i & 63) == 0) {
                    int wi = i >> 6;
                    cur = (wi < 64) ? __shfl(sup0, wi) : __shfl(sup1, wi - 64);
                }
                if (!((cur >> (i & 63)) & 1ull)) {
                    sup0 |= w0[r]; sup1 |= w1[r]; cur |= wd[r];
                }
            }
        }
        // 3. stage chunk c+1 into the other LDS buffer
        if (doload) {
            ulonglong2* dst = (ulonglong2*)buf[(c + 1) & 1];
            #pragma unroll
            for (int j = 0; j < 6; ++j) {
                int p = tid + j * 256;
                if (p < SCAN_CP) dst[p] = r0[j];
            }
        }
        __syncthreads();
    }
    if (wave == 0) {
        keep[(size_t)z * NMS_W + lane] = ~sup0;
        if (has1) keep[(size_t)z * NMS_W + 64 + lane] = ~sup1;
    }
}

// ---------------- K8: combine keeps, compact, write output ----------------
__global__ void k_final(const u64* __restrict__ keepw, const float* __restrict__ boxes,
                        float* __restrict__ out, int B) {
    int b = blockIdx.x;
    __shared__ u64 comb[NMS_W];
    __shared__ u32 pref[NMS_W + 1];
    int t = threadIdx.x;   // block = 128
    if (t < NMS_W) {
        u64 c = keepw[(size_t)(b * 2 + 0) * NMS_W + t] & keepw[(size_t)(b * 2 + 1) * NMS_W + t];
        if (t == NMS_W - 1) c &= (1ull << (PRE_NMS - 64 * (NMS_W - 1))) - 1ull;
        comb[t] = c;
    }
    __syncthreads();
    if (t == 0) {
        u32 acc = 0;
        for (int w = 0; w < NMS_W; ++w) { pref[w] = acc; acc += (u32)__popcll(comb[w]); }
        pref[NMS_W] = acc;
    }
    __syncthreads();
    u32 nk = pref[NMS_W];
    const float* bl = boxes + (size_t)(b * 2 + 0) * PRE_NMS * 4;
    const float* br = boxes + (size_t)(b * 2 + 1) * PRE_NMS * 4;
    float* outL = out + (size_t)b * POST_NMS * 5;
    float* outR = out + (size_t)B * POST_NMS * 5 + (size_t)b * POST_NMS * 5;
    if (t < NMS_W) {
        u64 c = comb[t];
        u32 r = pref[t];
        while (c) {
            int bit = __ffsll((long long)c) - 1;
            c &= c - 1;
            if (r < POST_NMS) {
                int i = t * 64 + bit;
                float4 L = ((const float4*)bl)[i];
                float4 R = ((const float4*)br)[i];
                outL[r * 5 + 0] = (float)b;
                outL[r * 5 + 1] = L.x; outL[r * 5 + 2] = L.y;
                outL[r * 5 + 3] = L.z; outL[r * 5 + 4] = L.w;
                outR[r * 5 + 0] = (float)b;
                outR[r * 5 + 1] = R.x; outR[r * 5 + 2] = R.y;
                outR[r * 5 + 3] = R.z; outR[r * 5 + 4] = R.w;
            }
            ++r;
        }
    }
    for (u32 r = nk + t; r < POST_NMS; r += blockDim.x) {
        outL[r * 5 + 0] = (float)b;
        outL[r * 5 + 1] = 0.f; outL[r * 5 + 2] = 0.f; outL[r * 5 + 3] = 0.f; outL[r * 5 + 4] = 0.f;
        outR[r * 5 + 0] = (float)b;
        outR[r * 5 + 1] = 0.f; outR[r * 5 + 2] = 0.f; outR[r * 5 + 3] = 0.f; outR[r * 5 + 4] = 0.f;
    }
}

extern "C" void kernel_launch(void* const* d_in, const int* in_sizes, int n_in,
                              void* d_out, int out_size, void* d_ws, size_t ws_size,
                              hipStream_t stream) {
    const float* scores  = (const float*)d_in[0];
    const float* deltas  = (const float*)d_in[1];
    const float* im_info = (const float*)d_in[2];
    const float* anchors = (const float*)d_in[3];
    int B = in_sizes[2] / 3;      // 2
    int N = in_sizes[3] / 4;      // 245520

    char* p = (char*)d_ws;
    auto alloc = [&](size_t bytes) -> char* {
        char* r = p;
        p += (bytes + 255) & ~(size_t)255;
        return r;
    };
    u32*  hist1 = (u32*) alloc((size_t)B * NBUCKET * 4);
    u32*  hist2 = (u32*) alloc((size_t)B * NBUCKET * 4);
    u32*  cnt   = (u32*) alloc((size_t)B * 4);
    u32*  t1    = (u32*) alloc((size_t)B * 4);
    u32*  t2    = (u32*) alloc((size_t)B * 4);
    u32*  above1= (u32*) alloc((size_t)B * 4);
    u64*  keys  = (u64*) alloc((size_t)B * CAP * 8);
    u32*  sel   = (u32*) alloc((size_t)B * PRE_NMS * 4);
    float* boxes = (float*)alloc((size_t)B * 2 * PRE_NMS * 4 * 4);
    u64*  keep  = (u64*) alloc((size_t)B * 2 * NMS_W * 8);
    u64*  masks = (u64*) alloc((size_t)B * 2 * PRE_NMS * NMS_W * 8);

    hipMemsetAsync(hist1, 0, (size_t)B * NBUCKET * 4, stream);
    hipMemsetAsync(hist2, 0, (size_t)B * NBUCKET * 4, stream);
    hipMemsetAsync(cnt,   0, (size_t)B * 4, stream);

    int total = B * N;
    const float2* scores2 = (const float2*)scores;
    dim3 hg(128, B);
    k_hist1  <<<hg, 256, 0, stream>>>(scores2, N, hist1);
    k_thresh1<<<B, 256, 0, stream>>>(hist1, t1, above1);
    k_hist2  <<<hg, 256, 0, stream>>>(scores2, N, t1, hist2);
    k_thresh2<<<B, 256, 0, stream>>>(hist2, above1, t2);
    k_gather <<<(total + 255) / 256, 256, 0, stream>>>(scores2, N, total, t1, t2, cnt, keys);
    k_sort   <<<B, 1024, 0, stream>>>(keys, cnt, sel);
    int dt = B * PRE_NMS;
    k_decode <<<(dt + 255) / 256, 256, 0, stream>>>(deltas, anchors, im_info, sel, N, dt, boxes);
    dim3 mg(NMS_W, NMS_W, B * 2);
    k_mask   <<<mg, 64, 0, stream>>>(boxes, masks);
    k_scan   <<<B * 2, 256, 0, stream>>>(masks, keep);
    k_final  <<<B, 128, 0, stream>>>(keep, boxes, (float*)d_out, B);
}

// Round 9
// 753.058 us; speedup vs baseline: 2.5099x; 1.0128x over previous
//
#include <hip/hip_runtime.h>
#include <cstdint>
#include <cstddef>
#include <math.h>

#pragma clang fp contract(off)

#define PRE_NMS    6000
#define POST_NMS   300
#define NMS_W      94          /* ceil(6000/64) */
#define NBUCKET    4096
#define CAP        8192
#define NMS_TH     0.7f

typedef unsigned int u32;
typedef unsigned long long u64;

// ---------------- K1a: coarse histogram on bits[31:20], LDS-privatized ----------------
__global__ void k_hist1(const float2* __restrict__ scores2, int N,
                        u32* __restrict__ hist) {
    int b = blockIdx.y;
    __shared__ u32 h[NBUCKET];
    for (int t = threadIdx.x; t < NBUCKET; t += blockDim.x) h[t] = 0;
    __syncthreads();
    for (int i = blockIdx.x * blockDim.x + threadIdx.x; i < N; i += gridDim.x * blockDim.x) {
        u32 bits = __float_as_uint(scores2[(size_t)b * N + i].y);
        atomicAdd(&h[bits >> 20], 1u);
    }
    __syncthreads();
    for (int t = threadIdx.x; t < NBUCKET; t += blockDim.x) {
        u32 v = h[t];
        if (v) atomicAdd(&hist[b * NBUCKET + t], v);
    }
}

// ---------------- K2a: coarse threshold bucket t1 + count strictly above ----------------
__global__ void k_thresh1(const u32* __restrict__ hist, u32* __restrict__ t1,
                          u32* __restrict__ above1) {
    int b = blockIdx.x;
    __shared__ u32 h[NBUCKET];
    __shared__ u32 part[256];
    for (int t = threadIdx.x; t < NBUCKET; t += blockDim.x) h[t] = hist[b * NBUCKET + t];
    __syncthreads();
    if (threadIdx.x < 256) {
        u32 s = 0;
        for (int j = 0; j < 16; ++j) s += h[threadIdx.x * 16 + j];
        part[threadIdx.x] = s;
    }
    __syncthreads();
    if (threadIdx.x == 0) {
        u32 acc = 0;
        int c;
        for (c = 255; c >= 0; --c) {
            if (acc + part[c] >= PRE_NMS) break;
            acc += part[c];
        }
        int t;
        for (t = c * 16 + 15; ; --t) {
            if (acc + h[t] >= PRE_NMS) break;
            acc += h[t];
        }
        t1[b] = (u32)t;
        above1[b] = acc;     // count with bucket strictly greater than t
    }
}

// ---------------- K1b: fine histogram of bucket-t1 elements on bits[19:8] ----------------
__global__ void k_hist2(const float2* __restrict__ scores2, int N,
                        const u32* __restrict__ t1, u32* __restrict__ hist2) {
    int b = blockIdx.y;
    u32 t1v = t1[b];
    __shared__ u32 h[NBUCKET];
    for (int t = threadIdx.x; t < NBUCKET; t += blockDim.x) h[t] = 0;
    __syncthreads();
    for (int i = blockIdx.x * blockDim.x + threadIdx.x; i < N; i += gridDim.x * blockDim.x) {
        u32 bits = __float_as_uint(scores2[(size_t)b * N + i].y);
        if ((bits >> 20) == t1v)
            atomicAdd(&h[(bits >> 8) & 0xFFFu], 1u);
    }
    __syncthreads();
    for (int t = threadIdx.x; t < NBUCKET; t += blockDim.x) {
        u32 v = h[t];
        if (v) atomicAdd(&hist2[b * NBUCKET + t], v);
    }
}

// ---------------- K2b: fine threshold t2 within bucket t1 ----------------
__global__ void k_thresh2(const u32* __restrict__ hist2, const u32* __restrict__ above1,
                          u32* __restrict__ t2) {
    int b = blockIdx.x;
    __shared__ u32 h[NBUCKET];
    __shared__ u32 part[256];
    for (int t = threadIdx.x; t < NBUCKET; t += blockDim.x) h[t] = hist2[b * NBUCKET + t];
    __syncthreads();
    if (threadIdx.x < 256) {
        u32 s = 0;
        for (int j = 0; j < 16; ++j) s += h[threadIdx.x * 16 + j];
        part[threadIdx.x] = s;
    }
    __syncthreads();
    if (threadIdx.x == 0) {
        u32 need = PRE_NMS - above1[b];   // >0 by construction of t1
        u32 acc = 0;
        int c;
        for (c = 255; c >= 0; --c) {
            if (acc + part[c] >= need) break;
            acc += part[c];
        }
        int t;
        for (t = c * 16 + 15; ; --t) {
            if (acc + h[t] >= need) break;
            acc += h[t];
        }
        t2[b] = (u32)t;
    }
}

// ---------------- K3: gather candidate keys ----------------
__global__ void k_gather(const float2* __restrict__ scores2, int N, int total,
                         const u32* __restrict__ t1, const u32* __restrict__ t2,
                         u32* __restrict__ cnt, u64* __restrict__ keys) {
    int idx = blockIdx.x * blockDim.x + threadIdx.x;
    if (idx >= total) return;
    int b = idx / N;
    int i = idx - b * N;
    u32 bits = __float_as_uint(scores2[idx].y);
    u32 bk = bits >> 20;
    u32 t1v = t1[b];
    bool take = (bk > t1v) || (bk == t1v && ((bits >> 8) & 0xFFFu) >= t2[b]);
    if (take) {
        u32 pos = atomicAdd(&cnt[b], 1u);
        if (pos < CAP)
            keys[(size_t)b * CAP + pos] = ((u64)bits << 32) | (u32)(~i);
    }
}

// ---------------- K4: bitonic sort 8192 keys, write top-6000 indices ----------------
__global__ __launch_bounds__(1024) void k_sort(const u64* __restrict__ keys,
                                               const u32* __restrict__ cnt,
                                               u32* __restrict__ sel) {
    int b = blockIdx.x;
    __shared__ u64 a[CAP];
    u32 c = cnt[b];
    if (c > CAP) c = CAP;
    for (int t = threadIdx.x; t < CAP; t += 1024)
        a[t] = (t < (int)c) ? keys[(size_t)b * CAP + t] : 0ull;
    __syncthreads();
    for (int k = 2; k <= CAP; k <<= 1) {
        for (int j = k >> 1; j > 0; j >>= 1) {
            for (int t = threadIdx.x; t < CAP / 2; t += 1024) {
                int i = ((t & ~(j - 1)) << 1) | (t & (j - 1));
                int p = i | j;
                u64 x = a[i], y = a[p];
                bool up = (i & k) == 0;
                bool sw = up ? (x < y) : (x > y);   // descending sort
                if (sw) { a[i] = y; a[p] = x; }
            }
            __syncthreads();
        }
    }
    for (int r = threadIdx.x; r < PRE_NMS; r += 1024)
        sel[b * PRE_NMS + r] = ~(u32)(a[r]);
}

// ---------------- K5: decode + clip selected boxes (left & right) ----------------
__global__ void k_decode(const float* __restrict__ deltas, const float* __restrict__ anchors,
                         const float* __restrict__ im_info, const u32* __restrict__ sel,
                         int N, int total, float* __restrict__ boxes) {
#pragma clang fp contract(off)
    int idx = blockIdx.x * blockDim.x + threadIdx.x;
    if (idx >= total) return;
    int b = idx / PRE_NMS;
    int r = idx - b * PRE_NMS;
    u32 i = sel[idx];
    float4 a = ((const float4*)anchors)[i];
    const float* d = deltas + ((size_t)b * N + i) * 6;
    float d0 = d[0], d1 = d[1], d2 = d[2], d3 = d[3], d4 = d[4], d5 = d[5];
    float w  = a.z - a.x + 1.0f;
    float h  = a.w - a.y + 1.0f;
    float cx = a.x + 0.5f * w;
    float cy = a.y + 0.5f * h;
    float Hm1 = im_info[b * 3 + 0] - 1.0f;
    float Wm1 = im_info[b * 3 + 1] - 1.0f;

    // correctly-rounded f32 exp via double (matches numpy's near-CR f32 exp)
    float e3 = (float)exp((double)d3);
    float e2 = (float)exp((double)d2);
    float e5 = (float)exp((double)d5);

    float pcy = d1 * h + cy;
    float ph  = e3 * h;
    float y1 = fminf(fmaxf(pcy - 0.5f * ph, 0.0f), Hm1);
    float y2 = fminf(fmaxf(pcy + 0.5f * ph, 0.0f), Hm1);

    {   // left: dx=d0, dw=d2
        float pcx = d0 * w + cx;
        float pw  = e2 * w;
        float x1 = fminf(fmaxf(pcx - 0.5f * pw, 0.0f), Wm1);
        float x2 = fminf(fmaxf(pcx + 0.5f * pw, 0.0f), Wm1);
        float* o = boxes + ((size_t)(b * 2 + 0) * PRE_NMS + r) * 4;
        o[0] = x1; o[1] = y1; o[2] = x2; o[3] = y2;
    }
    {   // right: dx=d4, dw=d5
        float pcx = d4 * w + cx;
        float pw  = e5 * w;
        float x1 = fminf(fmaxf(pcx - 0.5f * pw, 0.0f), Wm1);
        float x2 = fminf(fmaxf(pcx + 0.5f * pw, 0.0f), Wm1);
        float* o = boxes + ((size_t)(b * 2 + 1) * PRE_NMS + r) * 4;
        o[0] = x1; o[1] = y1; o[2] = x2; o[3] = y2;
    }
}

// ---------------- K6: pairwise IoU bitmask, TRANSPOSED layout mT[w][row] ----------------
// word (row, colblock w) stored at mT[w*PRE_NMS + row]  -> coalesced stores
__global__ void k_mask(const float* __restrict__ boxes, u64* __restrict__ masks) {
#pragma clang fp contract(off)
    int z = blockIdx.z;
    const float* bx = boxes + (size_t)z * PRE_NMS * 4;
    u64* mT = masks + (size_t)z * NMS_W * PRE_NMS;
    int rowStart = blockIdx.y * 64;
    int colStart = blockIdx.x * 64;
    int row = rowStart + threadIdx.x;
    if (blockIdx.x < blockIdx.y) {           // all cols < row: zero word
        if (row < PRE_NMS) mT[(size_t)blockIdx.x * PRE_NMS + row] = 0ull;
        return;
    }
    __shared__ float4 cb[64];
    int col0 = colStart + threadIdx.x;
    cb[threadIdx.x] = (col0 < PRE_NMS) ? ((const float4*)bx)[col0] : make_float4(0.f, 0.f, 0.f, 0.f);
    __syncthreads();
    if (row >= PRE_NMS) return;
    float4 rb = ((const float4*)bx)[row];
    float rA = (rb.z - rb.x + 1.0f) * (rb.w - rb.y + 1.0f);
    u64 word = 0;
    #pragma unroll 4
    for (int c = 0; c < 64; ++c) {
        int col = colStart + c;
        if (col <= row || col >= PRE_NMS) continue;
        float4 q = cb[c];
        float xx1 = fmaxf(rb.x, q.x);
        float yy1 = fmaxf(rb.y, q.y);
        float xx2 = fminf(rb.z, q.z);
        float yy2 = fminf(rb.w, q.w);
        float iw = fmaxf(xx2 - xx1 + 1.0f, 0.0f);
        float ih = fmaxf(yy2 - yy1 + 1.0f, 0.0f);
        float inter = iw * ih;
        float qA = (q.z - q.x + 1.0f) * (q.w - q.y + 1.0f);
        float iou = inter / (rA + qA - inter);
        if (iou > NMS_TH) word |= (1ull << c);
    }
    mT[(size_t)blockIdx.x * PRE_NMS + row] = word;
}

// ---------------- K7: sequential greedy scan, 8-wave producer + depth-2 pipeline ----------
// 1 block (512 thr) per image-side. Transposed global; row-major LDS chunks of 32 rows.
// Per chunk: ds_write regs(c+1) -> buf; issue loads(c+2) -> regs; wave0 PROC(c); barrier.
#define SCAN_R  32
#define SCAN_CW (SCAN_R * NMS_W)            /* 3008 words per chunk */
#define SCAN_CP (SCAN_CW / 2)               /* 1504 u64-pairs */
#define SCAN_T  512
#define SCAN_J  3                           /* ceil(1504/512) */

__device__ __forceinline__ void scan_issue(const u64* __restrict__ mT, int c, int nC,
                                           int tid, ulonglong2* r) {
    bool doload = c < nC;
    int R0 = c * SCAN_R;
    #pragma unroll
    for (int j = 0; j < SCAN_J; ++j) {
        int p = tid + j * SCAN_T;
        int w = p >> 4;                  // p / 16
        int rp = p & 15;                 // pair index within column segment
        int rabs = R0 + rp * 2;
        bool ok = doload && p < SCAN_CP && rabs < PRE_NMS;
        r[j] = ok ? *(const ulonglong2*)(mT + (size_t)w * PRE_NMS + rabs)
                  : make_ulonglong2(0ull, 0ull);
    }
}

__device__ __forceinline__ void scan_write(u64* __restrict__ dst, int tid,
                                           const ulonglong2* r) {
    #pragma unroll
    for (int j = 0; j < SCAN_J; ++j) {
        int p = tid + j * SCAN_T;
        if (p < SCAN_CP) {
            int w = p >> 4;
            int rp = p & 15;
            dst[(2 * rp) * NMS_W + w]     = r[j].x;
            dst[(2 * rp + 1) * NMS_W + w] = r[j].y;
        }
    }
}

__global__ __launch_bounds__(SCAN_T, 1) void k_scan(const u64* __restrict__ masks,
                                                    u64* __restrict__ keep) {
    int z = blockIdx.x;
    const u64* mT = masks + (size_t)z * NMS_W * PRE_NMS;
    __shared__ __align__(16) u64 buf[2][SCAN_CW];   // 48128 B
    int tid = threadIdx.x;
    int lane = tid & 63;
    int wave = tid >> 6;
    bool has1 = (lane + 64) < NMS_W;
    const int nC = (PRE_NMS + SCAN_R - 1) / SCAN_R;      // 188 (even)

    u64 sup0 = 0, sup1 = 0, cur = 0;
    ulonglong2 rA[SCAN_J], rB[SCAN_J];

    // prologue: chunk0 -> rA -> buf[0]; chunk1 -> rB (in flight)
    scan_issue(mT, 0, nC, tid, rA);
    scan_issue(mT, 1, nC, tid, rB);
    scan_write(buf[0], tid, rA);        // waits rA (and rB) loads
    __syncthreads();

    #define SCAN_PROC(CIDX, BI)                                                   \
    if (wave == 0) {                                                              \
        u64 w0[SCAN_R], w1[SCAN_R], wd[SCAN_R];                                   \
        _Pragma("unroll")                                                         \
        for (int r = 0; r < SCAN_R; ++r) {                                        \
            int i = (CIDX) * SCAN_R + r;                                          \
            w0[r] = buf[BI][r * NMS_W + lane];                                    \
            w1[r] = has1 ? buf[BI][r * NMS_W + 64 + lane] : 0ull;                 \
            wd[r] = buf[BI][r * NMS_W + (i >> 6)];                                \
        }                                                                         \
        __builtin_amdgcn_sched_barrier(0);                                        \
        _Pragma("unroll")                                                         \
        for (int r = 0; r < SCAN_R; ++r) {                                        \
            int i = (CIDX) * SCAN_R + r;                                          \
            if ((i & 63) == 0) {                                                  \
                int wi = i >> 6;                                                  \
                cur = (wi < 64) ? __shfl(sup0, wi) : __shfl(sup1, wi - 64);       \
            }                                                                     \
            if (i < PRE_NMS && !((cur >> (i & 63)) & 1ull)) {                     \
                sup0 |= w0[r]; sup1 |= w1[r]; cur |= wd[r];                       \
            }                                                                     \
        }                                                                         \
    }

    for (int c = 0; c < nC; c += 2) {
        // even body: buf[1] <- rB (chunk c+1); issue rA <- chunk c+2; PROC chunk c (buf[0])
        if (c + 1 < nC) scan_write(buf[1], tid, rB);
        scan_issue(mT, c + 2, nC, tid, rA);
        SCAN_PROC(c, 0)
        __syncthreads();
        // odd body: buf[0] <- rA (chunk c+2); issue rB <- chunk c+3; PROC chunk c+1 (buf[1])
        if (c + 1 < nC) {
            if (c + 2 < nC) scan_write(buf[0], tid, rA);
            scan_issue(mT, c + 3, nC, tid, rB);
            SCAN_PROC(c + 1, 1)
            __syncthreads();
        }
    }
    if (wave == 0) {
        keep[(size_t)z * NMS_W + lane] = ~sup0;
        if (has1) keep[(size_t)z * NMS_W + 64 + lane] = ~sup1;
    }
}

// ---------------- K8: combine keeps, compact, write output ----------------
__global__ void k_final(const u64* __restrict__ keepw, const float* __restrict__ boxes,
                        float* __restrict__ out, int B) {
    int b = blockIdx.x;
    __shared__ u64 comb[NMS_W];
    __shared__ u32 pref[NMS_W + 1];
    int t = threadIdx.x;   // block = 128
    if (t < NMS_W) {
        u64 c = keepw[(size_t)(b * 2 + 0) * NMS_W + t] & keepw[(size_t)(b * 2 + 1) * NMS_W + t];
        if (t == NMS_W - 1) c &= (1ull << (PRE_NMS - 64 * (NMS_W - 1))) - 1ull;
        comb[t] = c;
    }
    __syncthreads();
    if (t == 0) {
        u32 acc = 0;
        for (int w = 0; w < NMS_W; ++w) { pref[w] = acc; acc += (u32)__popcll(comb[w]); }
        pref[NMS_W] = acc;
    }
    __syncthreads();
    u32 nk = pref[NMS_W];
    const float* bl = boxes + (size_t)(b * 2 + 0) * PRE_NMS * 4;
    const float* br = boxes + (size_t)(b * 2 + 1) * PRE_NMS * 4;
    float* outL = out + (size_t)b * POST_NMS * 5;
    float* outR = out + (size_t)B * POST_NMS * 5 + (size_t)b * POST_NMS * 5;
    if (t < NMS_W) {
        u64 c = comb[t];
        u32 r = pref[t];
        while (c) {
            int bit = __ffsll((long long)c) - 1;
            c &= c - 1;
            if (r < POST_NMS) {
                int i = t * 64 + bit;
                float4 L = ((const float4*)bl)[i];
                float4 R = ((const float4*)br)[i];
                outL[r * 5 + 0] = (float)b;
                outL[r * 5 + 1] = L.x; outL[r * 5 + 2] = L.y;
                outL[r * 5 + 3] = L.z; outL[r * 5 + 4] = L.w;
                outR[r * 5 + 0] = (float)b;
                outR[r * 5 + 1] = R.x; outR[r * 5 + 2] = R.y;
                outR[r * 5 + 3] = R.z; outR[r * 5 + 4] = R.w;
            }
            ++r;
        }
    }
    for (u32 r = nk + t; r < POST_NMS; r += blockDim.x) {
        outL[r * 5 + 0] = (float)b;
        outL[r * 5 + 1] = 0.f; outL[r * 5 + 2] = 0.f; outL[r * 5 + 3] = 0.f; outL[r * 5 + 4] = 0.f;
        outR[r * 5 + 0] = (float)b;
        outR[r * 5 + 1] = 0.f; outR[r * 5 + 2] = 0.f; outR[r * 5 + 3] = 0.f; outR[r * 5 + 4] = 0.f;
    }
}

extern "C" void kernel_launch(void* const* d_in, const int* in_sizes, int n_in,
                              void* d_out, int out_size, void* d_ws, size_t ws_size,
                              hipStream_t stream) {
    const float* scores  = (const float*)d_in[0];
    const float* deltas  = (const float*)d_in[1];
    const float* im_info = (const float*)d_in[2];
    const float* anchors = (const float*)d_in[3];
    int B = in_sizes[2] / 3;      // 2
    int N = in_sizes[3] / 4;      // 245520

    char* p = (char*)d_ws;
    auto alloc = [&](size_t bytes) -> char* {
        char* r = p;
        p += (bytes + 255) & ~(size_t)255;
        return r;
    };
    u32*  hist1 = (u32*) alloc((size_t)B * NBUCKET * 4);
    u32*  hist2 = (u32*) alloc((size_t)B * NBUCKET * 4);
    u32*  cnt   = (u32*) alloc((size_t)B * 4);
    u32*  t1    = (u32*) alloc((size_t)B * 4);
    u32*  t2    = (u32*) alloc((size_t)B * 4);
    u32*  above1= (u32*) alloc((size_t)B * 4);
    u64*  keys  = (u64*) alloc((size_t)B * CAP * 8);
    u32*  sel   = (u32*) alloc((size_t)B * PRE_NMS * 4);
    float* boxes = (float*)alloc((size_t)B * 2 * PRE_NMS * 4 * 4);
    u64*  keep  = (u64*) alloc((size_t)B * 2 * NMS_W * 8);
    u64*  masks = (u64*) alloc((size_t)B * 2 * (size_t)NMS_W * PRE_NMS * 8);

    hipMemsetAsync(hist1, 0, (size_t)B * NBUCKET * 4, stream);
    hipMemsetAsync(hist2, 0, (size_t)B * NBUCKET * 4, stream);
    hipMemsetAsync(cnt,   0, (size_t)B * 4, stream);

    int total = B * N;
    const float2* scores2 = (const float2*)scores;
    dim3 hg(128, B);
    k_hist1  <<<hg, 256, 0, stream>>>(scores2, N, hist1);
    k_thresh1<<<B, 256, 0, stream>>>(hist1, t1, above1);
    k_hist2  <<<hg, 256, 0, stream>>>(scores2, N, t1, hist2);
    k_thresh2<<<B, 256, 0, stream>>>(hist2, above1, t2);
    k_gather <<<(total + 255) / 256, 256, 0, stream>>>(scores2, N, total, t1, t2, cnt, keys);
    k_sort   <<<B, 1024, 0, stream>>>(keys, cnt, sel);
    int dt = B * PRE_NMS;
    k_decode <<<(dt + 255) / 256, 256, 0, stream>>>(deltas, anchors, im_info, sel, N, dt, boxes);
    dim3 mg(NMS_W, NMS_W, B * 2);
    k_mask   <<<mg, 64, 0, stream>>>(boxes, masks);
    k_scan   <<<B * 2, SCAN_T, 0, stream>>>(masks, keep);
    k_final  <<<B, 128, 0, stream>>>(keep, boxes, (float*)d_out, B);
}

// Round 10
// 721.032 us; speedup vs baseline: 2.6213x; 1.0444x over previous
//
#include <hip/hip_runtime.h>
#include <cstdint>
#include <cstddef>
#include <math.h>

#pragma clang fp contract(off)

#define PRE_NMS    6000
#define POST_NMS   300
#define NMS_W      94          /* ceil(6000/64) */
#define NBUCKET    4096
#define CAP        8192
#define NMS_TH     0.7f

typedef unsigned int u32;
typedef unsigned long long u64;

// ---------------- K1a: coarse histogram on bits[31:20], LDS-privatized ----------------
__global__ void k_hist1(const float2* __restrict__ scores2, int N,
                        u32* __restrict__ hist) {
    int b = blockIdx.y;
    __shared__ u32 h[NBUCKET];
    for (int t = threadIdx.x; t < NBUCKET; t += blockDim.x) h[t] = 0;
    __syncthreads();
    for (int i = blockIdx.x * blockDim.x + threadIdx.x; i < N; i += gridDim.x * blockDim.x) {
        u32 bits = __float_as_uint(scores2[(size_t)b * N + i].y);
        atomicAdd(&h[bits >> 20], 1u);
    }
    __syncthreads();
    for (int t = threadIdx.x; t < NBUCKET; t += blockDim.x) {
        u32 v = h[t];
        if (v) atomicAdd(&hist[b * NBUCKET + t], v);
    }
}

// ---------------- K2a: coarse threshold bucket t1 + count strictly above ----------------
__global__ void k_thresh1(const u32* __restrict__ hist, u32* __restrict__ t1,
                          u32* __restrict__ above1) {
    int b = blockIdx.x;
    __shared__ u32 h[NBUCKET];
    __shared__ u32 part[256];
    for (int t = threadIdx.x; t < NBUCKET; t += blockDim.x) h[t] = hist[b * NBUCKET + t];
    __syncthreads();
    if (threadIdx.x < 256) {
        u32 s = 0;
        for (int j = 0; j < 16; ++j) s += h[threadIdx.x * 16 + j];
        part[threadIdx.x] = s;
    }
    __syncthreads();
    if (threadIdx.x == 0) {
        u32 acc = 0;
        int c;
        for (c = 255; c >= 0; --c) {
            if (acc + part[c] >= PRE_NMS) break;
            acc += part[c];
        }
        int t;
        for (t = c * 16 + 15; ; --t) {
            if (acc + h[t] >= PRE_NMS) break;
            acc += h[t];
        }
        t1[b] = (u32)t;
        above1[b] = acc;     // count with bucket strictly greater than t
    }
}

// ---------------- K1b: fine histogram of bucket-t1 elements on bits[19:8] ----------------
__global__ void k_hist2(const float2* __restrict__ scores2, int N,
                        const u32* __restrict__ t1, u32* __restrict__ hist2) {
    int b = blockIdx.y;
    u32 t1v = t1[b];
    __shared__ u32 h[NBUCKET];
    for (int t = threadIdx.x; t < NBUCKET; t += blockDim.x) h[t] = 0;
    __syncthreads();
    for (int i = blockIdx.x * blockDim.x + threadIdx.x; i < N; i += gridDim.x * blockDim.x) {
        u32 bits = __float_as_uint(scores2[(size_t)b * N + i].y);
        if ((bits >> 20) == t1v)
            atomicAdd(&h[(bits >> 8) & 0xFFFu], 1u);
    }
    __syncthreads();
    for (int t = threadIdx.x; t < NBUCKET; t += blockDim.x) {
        u32 v = h[t];
        if (v) atomicAdd(&hist2[b * NBUCKET + t], v);
    }
}

// ---------------- K2b: fine threshold t2 within bucket t1 ----------------
__global__ void k_thresh2(const u32* __restrict__ hist2, const u32* __restrict__ above1,
                          u32* __restrict__ t2) {
    int b = blockIdx.x;
    __shared__ u32 h[NBUCKET];
    __shared__ u32 part[256];
    for (int t = threadIdx.x; t < NBUCKET; t += blockDim.x) h[t] = hist2[b * NBUCKET + t];
    __syncthreads();
    if (threadIdx.x < 256) {
        u32 s = 0;
        for (int j = 0; j < 16; ++j) s += h[threadIdx.x * 16 + j];
        part[threadIdx.x] = s;
    }
    __syncthreads();
    if (threadIdx.x == 0) {
        u32 need = PRE_NMS - above1[b];   // >0 by construction of t1
        u32 acc = 0;
        int c;
        for (c = 255; c >= 0; --c) {
            if (acc + part[c] >= need) break;
            acc += part[c];
        }
        int t;
        for (t = c * 16 + 15; ; --t) {
            if (acc + h[t] >= need) break;
            acc += h[t];
        }
        t2[b] = (u32)t;
    }
}

// ---------------- K3: gather candidate keys ----------------
__global__ void k_gather(const float2* __restrict__ scores2, int N, int total,
                         const u32* __restrict__ t1, const u32* __restrict__ t2,
                         u32* __restrict__ cnt, u64* __restrict__ keys) {
    int idx = blockIdx.x * blockDim.x + threadIdx.x;
    if (idx >= total) return;
    int b = idx / N;
    int i = idx - b * N;
    u32 bits = __float_as_uint(scores2[idx].y);
    u32 bk = bits >> 20;
    u32 t1v = t1[b];
    bool take = (bk > t1v) || (bk == t1v && ((bits >> 8) & 0xFFFu) >= t2[b]);
    if (take) {
        u32 pos = atomicAdd(&cnt[b], 1u);
        if (pos < CAP)
            keys[(size_t)b * CAP + pos] = ((u64)bits << 32) | (u32)(~i);
    }
}

// ---------------- K4: bitonic sort 8192 keys, write top-6000 indices ----------------
__global__ __launch_bounds__(1024) void k_sort(const u64* __restrict__ keys,
                                               const u32* __restrict__ cnt,
                                               u32* __restrict__ sel) {
    int b = blockIdx.x;
    __shared__ u64 a[CAP];
    u32 c = cnt[b];
    if (c > CAP) c = CAP;
    for (int t = threadIdx.x; t < CAP; t += 1024)
        a[t] = (t < (int)c) ? keys[(size_t)b * CAP + t] : 0ull;
    __syncthreads();
    for (int k = 2; k <= CAP; k <<= 1) {
        for (int j = k >> 1; j > 0; j >>= 1) {
            for (int t = threadIdx.x; t < CAP / 2; t += 1024) {
                int i = ((t & ~(j - 1)) << 1) | (t & (j - 1));
                int p = i | j;
                u64 x = a[i], y = a[p];
                bool up = (i & k) == 0;
                bool sw = up ? (x < y) : (x > y);   // descending sort
                if (sw) { a[i] = y; a[p] = x; }
            }
            __syncthreads();
        }
    }
    for (int r = threadIdx.x; r < PRE_NMS; r += 1024)
        sel[b * PRE_NMS + r] = ~(u32)(a[r]);
}

// ---------------- K5: decode + clip selected boxes (left & right) ----------------
__global__ void k_decode(const float* __restrict__ deltas, const float* __restrict__ anchors,
                         const float* __restrict__ im_info, const u32* __restrict__ sel,
                         int N, int total, float* __restrict__ boxes) {
#pragma clang fp contract(off)
    int idx = blockIdx.x * blockDim.x + threadIdx.x;
    if (idx >= total) return;
    int b = idx / PRE_NMS;
    int r = idx - b * PRE_NMS;
    u32 i = sel[idx];
    float4 a = ((const float4*)anchors)[i];
    const float* d = deltas + ((size_t)b * N + i) * 6;
    float d0 = d[0], d1 = d[1], d2 = d[2], d3 = d[3], d4 = d[4], d5 = d[5];
    float w  = a.z - a.x + 1.0f;
    float h  = a.w - a.y + 1.0f;
    float cx = a.x + 0.5f * w;
    float cy = a.y + 0.5f * h;
    float Hm1 = im_info[b * 3 + 0] - 1.0f;
    float Wm1 = im_info[b * 3 + 1] - 1.0f;

    // correctly-rounded f32 exp via double (matches numpy's near-CR f32 exp)
    float e3 = (float)exp((double)d3);
    float e2 = (float)exp((double)d2);
    float e5 = (float)exp((double)d5);

    float pcy = d1 * h + cy;
    float ph  = e3 * h;
    float y1 = fminf(fmaxf(pcy - 0.5f * ph, 0.0f), Hm1);
    float y2 = fminf(fmaxf(pcy + 0.5f * ph, 0.0f), Hm1);

    {   // left: dx=d0, dw=d2
        float pcx = d0 * w + cx;
        float pw  = e2 * w;
        float x1 = fminf(fmaxf(pcx - 0.5f * pw, 0.0f), Wm1);
        float x2 = fminf(fmaxf(pcx + 0.5f * pw, 0.0f), Wm1);
        float* o = boxes + ((size_t)(b * 2 + 0) * PRE_NMS + r) * 4;
        o[0] = x1; o[1] = y1; o[2] = x2; o[3] = y2;
    }
    {   // right: dx=d4, dw=d5
        float pcx = d4 * w + cx;
        float pw  = e5 * w;
        float x1 = fminf(fmaxf(pcx - 0.5f * pw, 0.0f), Wm1);
        float x2 = fminf(fmaxf(pcx + 0.5f * pw, 0.0f), Wm1);
        float* o = boxes + ((size_t)(b * 2 + 1) * PRE_NMS + r) * 4;
        o[0] = x1; o[1] = y1; o[2] = x2; o[3] = y2;
    }
}

// ---------------- K6: pairwise IoU bitmask, TRANSPOSED layout mT[w][row] ----------------
// word (row, colblock w) stored at mT[w*PRE_NMS + row]  -> coalesced stores
__global__ void k_mask(const float* __restrict__ boxes, u64* __restrict__ masks) {
#pragma clang fp contract(off)
    int z = blockIdx.z;
    const float* bx = boxes + (size_t)z * PRE_NMS * 4;
    u64* mT = masks + (size_t)z * NMS_W * PRE_NMS;
    int rowStart = blockIdx.y * 64;
    int colStart = blockIdx.x * 64;
    int row = rowStart + threadIdx.x;
    if (blockIdx.x < blockIdx.y) {           // all cols < row: zero word
        if (row < PRE_NMS) mT[(size_t)blockIdx.x * PRE_NMS + row] = 0ull;
        return;
    }
    __shared__ float4 cb[64];
    int col0 = colStart + threadIdx.x;
    cb[threadIdx.x] = (col0 < PRE_NMS) ? ((const float4*)bx)[col0] : make_float4(0.f, 0.f, 0.f, 0.f);
    __syncthreads();
    if (row >= PRE_NMS) return;
    float4 rb = ((const float4*)bx)[row];
    float rA = (rb.z - rb.x + 1.0f) * (rb.w - rb.y + 1.0f);
    u64 word = 0;
    #pragma unroll 4
    for (int c = 0; c < 64; ++c) {
        int col = colStart + c;
        if (col <= row || col >= PRE_NMS) continue;
        float4 q = cb[c];
        float xx1 = fmaxf(rb.x, q.x);
        float yy1 = fmaxf(rb.y, q.y);
        float xx2 = fminf(rb.z, q.z);
        float yy2 = fminf(rb.w, q.w);
        float iw = fmaxf(xx2 - xx1 + 1.0f, 0.0f);
        float ih = fmaxf(yy2 - yy1 + 1.0f, 0.0f);
        float inter = iw * ih;
        float qA = (q.z - q.x + 1.0f) * (q.w - q.y + 1.0f);
        float iou = inter / (rA + qA - inter);
        if (iou > NMS_TH) word |= (1ull << c);
    }
    mT[(size_t)blockIdx.x * PRE_NMS + row] = word;
}

// ---------------- K7: sequential greedy scan, 8-wave producer + depth-2 pipeline ----------
// Raw s_barrier (NO vmcnt drain) keeps prefetch loads in flight across phases;
// only lgkmcnt(0) is waited (DS-write visibility). LDS row pitch 97 u64 kills the
// write-scatter bank conflict (424K conflicts in round 9).
#define SCAN_R   32
#define SCAN_CP  (SCAN_R * NMS_W / 2)       /* 1504 u64-pairs per chunk */
#define SCAN_T   512
#define SCAN_J   3                          /* ceil(1504/512) */
#define SCAN_PITCH 97                       /* u64 pitch per row in LDS */

__device__ __forceinline__ void scan_issue(const u64* __restrict__ mT, int c, int nC,
                                           int tid, ulonglong2* r) {
    bool doload = c < nC;
    int R0 = c * SCAN_R;
    #pragma unroll
    for (int j = 0; j < SCAN_J; ++j) {
        int p = tid + j * SCAN_T;
        int w = p >> 4;                  // p / 16
        int rp = p & 15;                 // pair index within column segment
        int rabs = R0 + rp * 2;
        bool ok = doload && p < SCAN_CP && rabs < PRE_NMS;
        r[j] = ok ? *(const ulonglong2*)(mT + (size_t)w * PRE_NMS + rabs)
                  : make_ulonglong2(0ull, 0ull);
    }
}

__device__ __forceinline__ void scan_write(u64* __restrict__ dst, int tid,
                                           const ulonglong2* r) {
    #pragma unroll
    for (int j = 0; j < SCAN_J; ++j) {
        int p = tid + j * SCAN_T;
        if (p < SCAN_CP) {
            int w = p >> 4;
            int rp = p & 15;
            dst[(2 * rp) * SCAN_PITCH + w]     = r[j].x;
            dst[(2 * rp + 1) * SCAN_PITCH + w] = r[j].y;
        }
    }
}

__device__ __forceinline__ void scan_barrier() {
    asm volatile("s_waitcnt lgkmcnt(0)" ::: "memory");
    __builtin_amdgcn_sched_barrier(0);
    __builtin_amdgcn_s_barrier();        // raw barrier: vmcnt NOT drained
    __builtin_amdgcn_sched_barrier(0);
}

__global__ __launch_bounds__(SCAN_T, 1) void k_scan(const u64* __restrict__ masks,
                                                    u64* __restrict__ keep) {
    int z = blockIdx.x;
    const u64* mT = masks + (size_t)z * NMS_W * PRE_NMS;
    __shared__ __align__(16) u64 buf[2][SCAN_R * SCAN_PITCH];   // 49664 B
    int tid = threadIdx.x;
    int lane = tid & 63;
    int wave = tid >> 6;
    bool has1 = (lane + 64) < NMS_W;
    const int nC = (PRE_NMS + SCAN_R - 1) / SCAN_R;      // 188 (even)

    u64 sup0 = 0, sup1 = 0, cur = 0;
    ulonglong2 rA[SCAN_J], rB[SCAN_J];

    // prologue: chunk0 -> rA -> buf[0]; chunk1 -> rB (in flight)
    scan_issue(mT, 0, nC, tid, rA);
    scan_issue(mT, 1, nC, tid, rB);
    scan_write(buf[0], tid, rA);        // waits rA loads (counted)
    scan_barrier();

    #define SCAN_PROC(CIDX, BI)                                                   \
    if (wave == 0) {                                                              \
        u64 w0[SCAN_R], w1[SCAN_R], wd[SCAN_R];                                   \
        _Pragma("unroll")                                                         \
        for (int r = 0; r < SCAN_R; ++r) {                                        \
            int i = (CIDX) * SCAN_R + r;                                          \
            w0[r] = buf[BI][r * SCAN_PITCH + lane];                               \
            w1[r] = has1 ? buf[BI][r * SCAN_PITCH + 64 + lane] : 0ull;            \
            wd[r] = buf[BI][r * SCAN_PITCH + (i >> 6)];                           \
        }                                                                         \
        __builtin_amdgcn_sched_barrier(0);                                        \
        _Pragma("unroll")                                                         \
        for (int r = 0; r < SCAN_R; ++r) {                                        \
            int i = (CIDX) * SCAN_R + r;                                          \
            if ((i & 63) == 0) {                                                  \
                int wi = i >> 6;                                                  \
                cur = (wi < 64) ? __shfl(sup0, wi) : __shfl(sup1, wi - 64);       \
            }                                                                     \
            if (i < PRE_NMS && !((cur >> (i & 63)) & 1ull)) {                     \
                sup0 |= w0[r]; sup1 |= w1[r]; cur |= wd[r];                       \
            }                                                                     \
        }                                                                         \
    }

    for (int c = 0; c < nC; c += 2) {
        // even body: buf[1] <- rB (chunk c+1); issue rA <- chunk c+2; PROC chunk c (buf[0])
        if (c + 1 < nC) scan_write(buf[1], tid, rB);
        scan_issue(mT, c + 2, nC, tid, rA);
        SCAN_PROC(c, 0)
        scan_barrier();
        // odd body: buf[0] <- rA (chunk c+2); issue rB <- chunk c+3; PROC chunk c+1 (buf[1])
        if (c + 1 < nC) {
            if (c + 2 < nC) scan_write(buf[0], tid, rA);
            scan_issue(mT, c + 3, nC, tid, rB);
            SCAN_PROC(c + 1, 1)
            scan_barrier();
        }
    }
    if (wave == 0) {
        keep[(size_t)z * NMS_W + lane] = ~sup0;
        if (has1) keep[(size_t)z * NMS_W + 64 + lane] = ~sup1;
    }
}

// ---------------- K8: combine keeps, compact, write output ----------------
__global__ void k_final(const u64* __restrict__ keepw, const float* __restrict__ boxes,
                        float* __restrict__ out, int B) {
    int b = blockIdx.x;
    __shared__ u64 comb[NMS_W];
    __shared__ u32 pref[NMS_W + 1];
    int t = threadIdx.x;   // block = 128
    if (t < NMS_W) {
        u64 c = keepw[(size_t)(b * 2 + 0) * NMS_W + t] & keepw[(size_t)(b * 2 + 1) * NMS_W + t];
        if (t == NMS_W - 1) c &= (1ull << (PRE_NMS - 64 * (NMS_W - 1))) - 1ull;
        comb[t] = c;
    }
    __syncthreads();
    if (t == 0) {
        u32 acc = 0;
        for (int w = 0; w < NMS_W; ++w) { pref[w] = acc; acc += (u32)__popcll(comb[w]); }
        pref[NMS_W] = acc;
    }
    __syncthreads();
    u32 nk = pref[NMS_W];
    const float* bl = boxes + (size_t)(b * 2 + 0) * PRE_NMS * 4;
    const float* br = boxes + (size_t)(b * 2 + 1) * PRE_NMS * 4;
    float* outL = out + (size_t)b * POST_NMS * 5;
    float* outR = out + (size_t)B * POST_NMS * 5 + (size_t)b * POST_NMS * 5;
    if (t < NMS_W) {
        u64 c = comb[t];
        u32 r = pref[t];
        while (c) {
            int bit = __ffsll((long long)c) - 1;
            c &= c - 1;
            if (r < POST_NMS) {
                int i = t * 64 + bit;
                float4 L = ((const float4*)bl)[i];
                float4 R = ((const float4*)br)[i];
                outL[r * 5 + 0] = (float)b;
                outL[r * 5 + 1] = L.x; outL[r * 5 + 2] = L.y;
                outL[r * 5 + 3] = L.z; outL[r * 5 + 4] = L.w;
                outR[r * 5 + 0] = (float)b;
                outR[r * 5 + 1] = R.x; outR[r * 5 + 2] = R.y;
                outR[r * 5 + 3] = R.z; outR[r * 5 + 4] = R.w;
            }
            ++r;
        }
    }
    for (u32 r = nk + t; r < POST_NMS; r += blockDim.x) {
        outL[r * 5 + 0] = (float)b;
        outL[r * 5 + 1] = 0.f; outL[r * 5 + 2] = 0.f; outL[r * 5 + 3] = 0.f; outL[r * 5 + 4] = 0.f;
        outR[r * 5 + 0] = (float)b;
        outR[r * 5 + 1] = 0.f; outR[r * 5 + 2] = 0.f; outR[r * 5 + 3] = 0.f; outR[r * 5 + 4] = 0.f;
    }
}

extern "C" void kernel_launch(void* const* d_in, const int* in_sizes, int n_in,
                              void* d_out, int out_size, void* d_ws, size_t ws_size,
                              hipStream_t stream) {
    const float* scores  = (const float*)d_in[0];
    const float* deltas  = (const float*)d_in[1];
    const float* im_info = (const float*)d_in[2];
    const float* anchors = (const float*)d_in[3];
    int B = in_sizes[2] / 3;      // 2
    int N = in_sizes[3] / 4;      // 245520

    char* p = (char*)d_ws;
    auto alloc = [&](size_t bytes) -> char* {
        char* r = p;
        p += (bytes + 255) & ~(size_t)255;
        return r;
    };
    u32*  hist1 = (u32*) alloc((size_t)B * NBUCKET * 4);
    u32*  hist2 = (u32*) alloc((size_t)B * NBUCKET * 4);
    u32*  cnt   = (u32*) alloc((size_t)B * 4);
    u32*  t1    = (u32*) alloc((size_t)B * 4);
    u32*  t2    = (u32*) alloc((size_t)B * 4);
    u32*  above1= (u32*) alloc((size_t)B * 4);
    u64*  keys  = (u64*) alloc((size_t)B * CAP * 8);
    u32*  sel   = (u32*) alloc((size_t)B * PRE_NMS * 4);
    float* boxes = (float*)alloc((size_t)B * 2 * PRE_NMS * 4 * 4);
    u64*  keep  = (u64*) alloc((size_t)B * 2 * NMS_W * 8);
    u64*  masks = (u64*) alloc((size_t)B * 2 * (size_t)NMS_W * PRE_NMS * 8);

    hipMemsetAsync(hist1, 0, (size_t)B * NBUCKET * 4, stream);
    hipMemsetAsync(hist2, 0, (size_t)B * NBUCKET * 4, stream);
    hipMemsetAsync(cnt,   0, (size_t)B * 4, stream);

    int total = B * N;
    const float2* scores2 = (const float2*)scores;
    dim3 hg(128, B);
    k_hist1  <<<hg, 256, 0, stream>>>(scores2, N, hist1);
    k_thresh1<<<B, 256, 0, stream>>>(hist1, t1, above1);
    k_hist2  <<<hg, 256, 0, stream>>>(scores2, N, t1, hist2);
    k_thresh2<<<B, 256, 0, stream>>>(hist2, above1, t2);
    k_gather <<<(total + 255) / 256, 256, 0, stream>>>(scores2, N, total, t1, t2, cnt, keys);
    k_sort   <<<B, 1024, 0, stream>>>(keys, cnt, sel);
    int dt = B * PRE_NMS;
    k_decode <<<(dt + 255) / 256, 256, 0, stream>>>(deltas, anchors, im_info, sel, N, dt, boxes);
    dim3 mg(NMS_W, NMS_W, B * 2);
    k_mask   <<<mg, 64, 0, stream>>>(boxes, masks);
    k_scan   <<<B * 2, SCAN_T, 0, stream>>>(masks, keep);
    k_final  <<<B, 128, 0, stream>>>(keep, boxes, (float*)d_out, B);
}

// Round 12
// 430.207 us; speedup vs baseline: 4.3934x; 1.6760x over previous
//
#include <hip/hip_runtime.h>
#include <cstdint>
#include <cstddef>
#include <math.h>

#pragma clang fp contract(off)

#define PRE_NMS    6000
#define POST_NMS   300
#define NMS_W      94          /* ceil(6000/64) */
#define NBUCKET    4096
#define CAP        8192
#define NMS_TH     0.7f

typedef unsigned int u32;
typedef unsigned long long u64;

// ---------------- K1a: coarse histogram on bits[31:20], LDS-privatized ----------------
__global__ void k_hist1(const float2* __restrict__ scores2, int N,
                        u32* __restrict__ hist) {
    int b = blockIdx.y;
    __shared__ u32 h[NBUCKET];
    for (int t = threadIdx.x; t < NBUCKET; t += blockDim.x) h[t] = 0;
    __syncthreads();
    for (int i = blockIdx.x * blockDim.x + threadIdx.x; i < N; i += gridDim.x * blockDim.x) {
        u32 bits = __float_as_uint(scores2[(size_t)b * N + i].y);
        atomicAdd(&h[bits >> 20], 1u);
    }
    __syncthreads();
    for (int t = threadIdx.x; t < NBUCKET; t += blockDim.x) {
        u32 v = h[t];
        if (v) atomicAdd(&hist[b * NBUCKET + t], v);
    }
}

// ---------------- K2a: coarse threshold bucket t1 + count strictly above ----------------
__global__ void k_thresh1(const u32* __restrict__ hist, u32* __restrict__ t1,
                          u32* __restrict__ above1) {
    int b = blockIdx.x;
    __shared__ u32 h[NBUCKET];
    __shared__ u32 part[256];
    for (int t = threadIdx.x; t < NBUCKET; t += blockDim.x) h[t] = hist[b * NBUCKET + t];
    __syncthreads();
    if (threadIdx.x < 256) {
        u32 s = 0;
        for (int j = 0; j < 16; ++j) s += h[threadIdx.x * 16 + j];
        part[threadIdx.x] = s;
    }
    __syncthreads();
    if (threadIdx.x == 0) {
        u32 acc = 0;
        int c;
        for (c = 255; c >= 0; --c) {
            if (acc + part[c] >= PRE_NMS) break;
            acc += part[c];
        }
        int t;
        for (t = c * 16 + 15; ; --t) {
            if (acc + h[t] >= PRE_NMS) break;
            acc += h[t];
        }
        t1[b] = (u32)t;
        above1[b] = acc;     // count with bucket strictly greater than t
    }
}

// ---------------- K1b: fine histogram of bucket-t1 elements on bits[19:8] ----------------
__global__ void k_hist2(const float2* __restrict__ scores2, int N,
                        const u32* __restrict__ t1, u32* __restrict__ hist2) {
    int b = blockIdx.y;
    u32 t1v = t1[b];
    __shared__ u32 h[NBUCKET];
    for (int t = threadIdx.x; t < NBUCKET; t += blockDim.x) h[t] = 0;
    __syncthreads();
    for (int i = blockIdx.x * blockDim.x + threadIdx.x; i < N; i += gridDim.x * blockDim.x) {
        u32 bits = __float_as_uint(scores2[(size_t)b * N + i].y);
        if ((bits >> 20) == t1v)
            atomicAdd(&h[(bits >> 8) & 0xFFFu], 1u);
    }
    __syncthreads();
    for (int t = threadIdx.x; t < NBUCKET; t += blockDim.x) {
        u32 v = h[t];
        if (v) atomicAdd(&hist2[b * NBUCKET + t], v);
    }
}

// ---------------- K2b: fine threshold t2 within bucket t1 ----------------
__global__ void k_thresh2(const u32* __restrict__ hist2, const u32* __restrict__ above1,
                          u32* __restrict__ t2) {
    int b = blockIdx.x;
    __shared__ u32 h[NBUCKET];
    __shared__ u32 part[256];
    for (int t = threadIdx.x; t < NBUCKET; t += blockDim.x) h[t] = hist2[b * NBUCKET + t];
    __syncthreads();
    if (threadIdx.x < 256) {
        u32 s = 0;
        for (int j = 0; j < 16; ++j) s += h[threadIdx.x * 16 + j];
        part[threadIdx.x] = s;
    }
    __syncthreads();
    if (threadIdx.x == 0) {
        u32 need = PRE_NMS - above1[b];   // >0 by construction of t1
        u32 acc = 0;
        int c;
        for (c = 255; c >= 0; --c) {
            if (acc + part[c] >= need) break;
            acc += part[c];
        }
        int t;
        for (t = c * 16 + 15; ; --t) {
            if (acc + h[t] >= need) break;
            acc += h[t];
        }
        t2[b] = (u32)t;
    }
}

// ---------------- K3: gather candidate keys ----------------
__global__ void k_gather(const float2* __restrict__ scores2, int N, int total,
                         const u32* __restrict__ t1, const u32* __restrict__ t2,
                         u32* __restrict__ cnt, u64* __restrict__ keys) {
    int idx = blockIdx.x * blockDim.x + threadIdx.x;
    if (idx >= total) return;
    int b = idx / N;
    int i = idx - b * N;
    u32 bits = __float_as_uint(scores2[idx].y);
    u32 bk = bits >> 20;
    u32 t1v = t1[b];
    bool take = (bk > t1v) || (bk == t1v && ((bits >> 8) & 0xFFFu) >= t2[b]);
    if (take) {
        u32 pos = atomicAdd(&cnt[b], 1u);
        if (pos < CAP)
            keys[(size_t)b * CAP + pos] = ((u64)bits << 32) | (u32)(~i);
    }
}

// ---------------- K4: bitonic sort 8192 keys, write top-6000 indices ----------------
__global__ __launch_bounds__(1024) void k_sort(const u64* __restrict__ keys,
                                               const u32* __restrict__ cnt,
                                               u32* __restrict__ sel) {
    int b = blockIdx.x;
    __shared__ u64 a[CAP];
    u32 c = cnt[b];
    if (c > CAP) c = CAP;
    for (int t = threadIdx.x; t < CAP; t += 1024)
        a[t] = (t < (int)c) ? keys[(size_t)b * CAP + t] : 0ull;
    __syncthreads();
    for (int k = 2; k <= CAP; k <<= 1) {
        for (int j = k >> 1; j > 0; j >>= 1) {
            for (int t = threadIdx.x; t < CAP / 2; t += 1024) {
                int i = ((t & ~(j - 1)) << 1) | (t & (j - 1));
                int p = i | j;
                u64 x = a[i], y = a[p];
                bool up = (i & k) == 0;
                bool sw = up ? (x < y) : (x > y);   // descending sort
                if (sw) { a[i] = y; a[p] = x; }
            }
            __syncthreads();
        }
    }
    for (int r = threadIdx.x; r < PRE_NMS; r += 1024)
        sel[b * PRE_NMS + r] = ~(u32)(a[r]);
}

// ---------------- K5: decode + clip selected boxes (left & right) ----------------
__global__ void k_decode(const float* __restrict__ deltas, const float* __restrict__ anchors,
                         const float* __restrict__ im_info, const u32* __restrict__ sel,
                         int N, int total, float* __restrict__ boxes) {
#pragma clang fp contract(off)
    int idx = blockIdx.x * blockDim.x + threadIdx.x;
    if (idx >= total) return;
    int b = idx / PRE_NMS;
    int r = idx - b * PRE_NMS;
    u32 i = sel[idx];
    float4 a = ((const float4*)anchors)[i];
    const float* d = deltas + ((size_t)b * N + i) * 6;
    float d0 = d[0], d1 = d[1], d2 = d[2], d3 = d[3], d4 = d[4], d5 = d[5];
    float w  = a.z - a.x + 1.0f;
    float h  = a.w - a.y + 1.0f;
    float cx = a.x + 0.5f * w;
    float cy = a.y + 0.5f * h;
    float Hm1 = im_info[b * 3 + 0] - 1.0f;
    float Wm1 = im_info[b * 3 + 1] - 1.0f;

    // correctly-rounded f32 exp via double (matches numpy's near-CR f32 exp)
    float e3 = (float)exp((double)d3);
    float e2 = (float)exp((double)d2);
    float e5 = (float)exp((double)d5);

    float pcy = d1 * h + cy;
    float ph  = e3 * h;
    float y1 = fminf(fmaxf(pcy - 0.5f * ph, 0.0f), Hm1);
    float y2 = fminf(fmaxf(pcy + 0.5f * ph, 0.0f), Hm1);

    {   // left: dx=d0, dw=d2
        float pcx = d0 * w + cx;
        float pw  = e2 * w;
        float x1 = fminf(fmaxf(pcx - 0.5f * pw, 0.0f), Wm1);
        float x2 = fminf(fmaxf(pcx + 0.5f * pw, 0.0f), Wm1);
        float* o = boxes + ((size_t)(b * 2 + 0) * PRE_NMS + r) * 4;
        o[0] = x1; o[1] = y1; o[2] = x2; o[3] = y2;
    }
    {   // right: dx=d4, dw=d5
        float pcx = d4 * w + cx;
        float pw  = e5 * w;
        float x1 = fminf(fmaxf(pcx - 0.5f * pw, 0.0f), Wm1);
        float x2 = fminf(fmaxf(pcx + 0.5f * pw, 0.0f), Wm1);
        float* o = boxes + ((size_t)(b * 2 + 1) * PRE_NMS + r) * 4;
        o[0] = x1; o[1] = y1; o[2] = x2; o[3] = y2;
    }
}

// ---------------- K6: pairwise IoU bitmask, row-major m[row][w] (upper triangle) --------
__global__ void k_mask(const float* __restrict__ boxes, u64* __restrict__ masks) {
#pragma clang fp contract(off)
    int z = blockIdx.z;
    const float* bx = boxes + (size_t)z * PRE_NMS * 4;
    u64* m = masks + (size_t)z * PRE_NMS * NMS_W;
    int rowStart = blockIdx.y * 64;
    int colStart = blockIdx.x * 64;
    int row = rowStart + threadIdx.x;
    if (blockIdx.x < blockIdx.y) {           // all cols < row: zero word
        if (row < PRE_NMS) m[(size_t)row * NMS_W + blockIdx.x] = 0ull;
        return;
    }
    __shared__ float4 cb[64];
    int col0 = colStart + threadIdx.x;
    cb[threadIdx.x] = (col0 < PRE_NMS) ? ((const float4*)bx)[col0] : make_float4(0.f, 0.f, 0.f, 0.f);
    __syncthreads();
    if (row >= PRE_NMS) return;
    float4 rb = ((const float4*)bx)[row];
    float rA = (rb.z - rb.x + 1.0f) * (rb.w - rb.y + 1.0f);
    u64 word = 0;
    #pragma unroll 4
    for (int c = 0; c < 64; ++c) {
        int col = colStart + c;
        if (col <= row || col >= PRE_NMS) continue;
        float4 q = cb[c];
        float xx1 = fmaxf(rb.x, q.x);
        float yy1 = fmaxf(rb.y, q.y);
        float xx2 = fminf(rb.z, q.z);
        float yy2 = fminf(rb.w, q.w);
        float iw = fmaxf(xx2 - xx1 + 1.0f, 0.0f);
        float ih = fmaxf(yy2 - yy1 + 1.0f, 0.0f);
        float inter = iw * ih;
        float qA = (q.z - q.x + 1.0f) * (q.w - q.y + 1.0f);
        float iou = inter / (rA + qA - inter);
        if (iou > NMS_TH) word |= (1ull << c);
    }
    m[(size_t)row * NMS_W + blockIdx.x] = word;
}

// ---------------- K7: joint early-exit tiled greedy scan (1 block / image) ----------------
// Per 64-row tile: (A) wave0 decides keeps for BOTH sides via diagonal words + ballot/
// readlane sparse chain; (B) all 8 waves OR only the KEPT rows' mask rows (coalesced)
// into LDS sup accumulators. Exit when >=300 combined survivors found (exact — output
// only needs the first 300; if fewer exist we scan everything and counts stay exact).
__global__ __launch_bounds__(512, 1) void k_scan(const u64* __restrict__ masks,
                                                 u64* __restrict__ comb) {
    int img = blockIdx.x;
    const u64* mL = masks + (size_t)(img * 2 + 0) * PRE_NMS * NMS_W;
    const u64* mR = masks + (size_t)(img * 2 + 1) * PRE_NMS * NMS_W;
    __shared__ u32 supL[NMS_W * 2], supR[NMS_W * 2];
    __shared__ u64 ldsKeepL, ldsKeepR;
    __shared__ u32 ldsCnt;
    int tid = threadIdx.x, lane = tid & 63, wave = tid >> 6;
    for (int i = tid; i < NMS_W * 2; i += 512) { supL[i] = 0; supR[i] = 0; }
    if (tid == 0) ldsCnt = 0;
    __syncthreads();

    u32 cnt = 0;
    int t = 0;
    for (; t < NMS_W; ++t) {
        int rows = PRE_NMS - t * 64; if (rows > 64) rows = 64;
        u64 valid = (rows == 64) ? ~0ull : ((1ull << rows) - 1ull);
        // ---- A-phase: wave 0 decides ----
        if (wave == 0) {
            int row = t * 64 + lane;
            u64 dgL = (lane < rows) ? mL[(size_t)row * NMS_W + t] : 0ull;
            u64 dgR = (lane < rows) ? mR[(size_t)row * NMS_W + t] : 0ull;
            u64 curL = ((u64)supL[2 * t + 1] << 32) | supL[2 * t];
            u64 curR = ((u64)supR[2 * t + 1] << 32) | supR[2 * t];
            u64 aliveL = ~curL & valid;
            u64 candL = __ballot(dgL != 0ull) & aliveL;
            while (candL) {
                int f = __ffsll((long long)candL) - 1;
                u64 df = __shfl(dgL, f);        // bits only > f (upper triangle)
                aliveL &= ~df;
                candL &= ~(1ull << f);
                candL &= aliveL;
            }
            u64 aliveR = ~curR & valid;
            u64 candR = __ballot(dgR != 0ull) & aliveR;
            while (candR) {
                int f = __ffsll((long long)candR) - 1;
                u64 df = __shfl(dgR, f);
                aliveR &= ~df;
                candR &= ~(1ull << f);
                candR &= aliveR;
            }
            u64 cw = aliveL & aliveR;
            cnt += (u32)__popcll(cw);
            if (lane == 0) {
                ldsKeepL = aliveL; ldsKeepR = aliveR; ldsCnt = cnt;
                comb[(size_t)img * NMS_W + t] = cw;
            }
        }
        __syncthreads();
        if (ldsCnt >= POST_NMS) { ++t; break; }   // comb[t] already written & counted
        // ---- B-phase: OR kept rows into sup (all waves) ----
        u64 kL = ldsKeepL, kR = ldsKeepR;
        u64 aL0 = 0, aL1 = 0, aR0 = 0, aR1 = 0;
        bool hi = (lane + 64) < NMS_W;
        #pragma unroll
        for (int k = 0; k < 8; ++k) {
            int r = wave + k * 8;
            size_t row = (size_t)(t * 64 + r);
            if ((kL >> r) & 1ull) {               // wave-uniform branch
                aL0 |= mL[row * NMS_W + lane];
                if (hi) aL1 |= mL[row * NMS_W + 64 + lane];
            }
            if ((kR >> r) & 1ull) {
                aR0 |= mR[row * NMS_W + lane];
                if (hi) aR1 |= mR[row * NMS_W + 64 + lane];
            }
        }
        if (aL0) { atomicOr(&supL[2 * lane], (u32)aL0); atomicOr(&supL[2 * lane + 1], (u32)(aL0 >> 32)); }
        if (hi && aL1) { atomicOr(&supL[2 * (lane + 64)], (u32)aL1); atomicOr(&supL[2 * (lane + 64) + 1], (u32)(aL1 >> 32)); }
        if (aR0) { atomicOr(&supR[2 * lane], (u32)aR0); atomicOr(&supR[2 * lane + 1], (u32)(aR0 >> 32)); }
        if (hi && aR1) { atomicOr(&supR[2 * (lane + 64)], (u32)aR1); atomicOr(&supR[2 * (lane + 64) + 1], (u32)(aR1 >> 32)); }
        __syncthreads();
    }
    // zero remaining comb words (ws is re-poisoned 0xAA every call)
    for (int w = t + tid; w < NMS_W; w += 512)
        comb[(size_t)img * NMS_W + w] = 0ull;
}

// ---------------- K8: compact combined keeps, write output ----------------
__global__ void k_final(const u64* __restrict__ combw, const float* __restrict__ boxes,
                        float* __restrict__ out, int B) {
    int b = blockIdx.x;
    __shared__ u64 comb[NMS_W];
    __shared__ u32 pref[NMS_W + 1];
    int t = threadIdx.x;   // block = 128
    if (t < NMS_W) {
        u64 c = combw[(size_t)b * NMS_W + t];
        if (t == NMS_W - 1) c &= (1ull << (PRE_NMS - 64 * (NMS_W - 1))) - 1ull;
        comb[t] = c;
    }
    __syncthreads();
    if (t == 0) {
        u32 acc = 0;
        for (int w = 0; w < NMS_W; ++w) { pref[w] = acc; acc += (u32)__popcll(comb[w]); }
        pref[NMS_W] = acc;
    }
    __syncthreads();
    u32 nk = pref[NMS_W];
    const float* bl = boxes + (size_t)(b * 2 + 0) * PRE_NMS * 4;
    const float* br = boxes + (size_t)(b * 2 + 1) * PRE_NMS * 4;
    float* outL = out + (size_t)b * POST_NMS * 5;
    float* outR = out + (size_t)B * POST_NMS * 5 + (size_t)b * POST_NMS * 5;
    if (t < NMS_W) {
        u64 c = comb[t];
        u32 r = pref[t];
        while (c) {
            int bit = __ffsll((long long)c) - 1;
            c &= c - 1;
            if (r < POST_NMS) {
                int i = t * 64 + bit;
                float4 L = ((const float4*)bl)[i];
                float4 R = ((const float4*)br)[i];
                outL[r * 5 + 0] = (float)b;
                outL[r * 5 + 1] = L.x; outL[r * 5 + 2] = L.y;
                outL[r * 5 + 3] = L.z; outL[r * 5 + 4] = L.w;
                outR[r * 5 + 0] = (float)b;
                outR[r * 5 + 1] = R.x; outR[r * 5 + 2] = R.y;
                outR[r * 5 + 3] = R.z; outR[r * 5 + 4] = R.w;
            }
            ++r;
        }
    }
    for (u32 r = nk + t; r < POST_NMS; r += blockDim.x) {
        outL[r * 5 + 0] = (float)b;
        outL[r * 5 + 1] = 0.f; outL[r * 5 + 2] = 0.f; outL[r * 5 + 3] = 0.f; outL[r * 5 + 4] = 0.f;
        outR[r * 5 + 0] = (float)b;
        outR[r * 5 + 1] = 0.f; outR[r * 5 + 2] = 0.f; outR[r * 5 + 3] = 0.f; outR[r * 5 + 4] = 0.f;
    }
}

extern "C" void kernel_launch(void* const* d_in, const int* in_sizes, int n_in,
                              void* d_out, int out_size, void* d_ws, size_t ws_size,
                              hipStream_t stream) {
    const float* scores  = (const float*)d_in[0];
    const float* deltas  = (const float*)d_in[1];
    const float* im_info = (const float*)d_in[2];
    const float* anchors = (const float*)d_in[3];
    int B = in_sizes[2] / 3;      // 2
    int N = in_sizes[3] / 4;      // 245520

    char* p = (char*)d_ws;
    auto alloc = [&](size_t bytes) -> char* {
        char* r = p;
        p += (bytes + 255) & ~(size_t)255;
        return r;
    };
    u32*  hist1 = (u32*) alloc((size_t)B * NBUCKET * 4);
    u32*  hist2 = (u32*) alloc((size_t)B * NBUCKET * 4);
    u32*  cnt   = (u32*) alloc((size_t)B * 4);
    u32*  t1    = (u32*) alloc((size_t)B * 4);
    u32*  t2    = (u32*) alloc((size_t)B * 4);
    u32*  above1= (u32*) alloc((size_t)B * 4);
    u64*  keys  = (u64*) alloc((size_t)B * CAP * 8);
    u32*  sel   = (u32*) alloc((size_t)B * PRE_NMS * 4);
    float* boxes = (float*)alloc((size_t)B * 2 * PRE_NMS * 4 * 4);
    u64*  comb  = (u64*) alloc((size_t)B * NMS_W * 8);
    u64*  masks = (u64*) alloc((size_t)B * 2 * (size_t)PRE_NMS * NMS_W * 8);

    hipMemsetAsync(hist1, 0, (size_t)B * NBUCKET * 4, stream);
    hipMemsetAsync(hist2, 0, (size_t)B * NBUCKET * 4, stream);
    hipMemsetAsync(cnt,   0, (size_t)B * 4, stream);

    int total = B * N;
    const float2* scores2 = (const float2*)scores;
    dim3 hg(128, B);
    k_hist1  <<<hg, 256, 0, stream>>>(scores2, N, hist1);
    k_thresh1<<<B, 256, 0, stream>>>(hist1, t1, above1);
    k_hist2  <<<hg, 256, 0, stream>>>(scores2, N, t1, hist2);
    k_thresh2<<<B, 256, 0, stream>>>(hist2, above1, t2);
    k_gather <<<(total + 255) / 256, 256, 0, stream>>>(scores2, N, total, t1, t2, cnt, keys);
    k_sort   <<<B, 1024, 0, stream>>>(keys, cnt, sel);
    int dt = B * PRE_NMS;
    k_decode <<<(dt + 255) / 256, 256, 0, stream>>>(deltas, anchors, im_info, sel, N, dt, boxes);
    dim3 mg(NMS_W, NMS_W, B * 2);
    k_mask   <<<mg, 64, 0, stream>>>(boxes, masks);
    k_scan   <<<B, 512, 0, stream>>>(masks, comb);
    k_final  <<<B, 128, 0, stream>>>(comb, boxes, (float*)d_out, B);
}

// Round 14
// 315.141 us; speedup vs baseline: 5.9975x; 1.3651x over previous
//
#include <hip/hip_runtime.h>
#include <cstdint>
#include <cstddef>
#include <math.h>

#pragma clang fp contract(off)

#define PRE_NMS    6000
#define POST_NMS   300
#define NMS_W      94          /* ceil(6000/64) */
#define NBUCKET    4096
#define CAP        8192
#define NMS_TH     0.7f

typedef unsigned int u32;
typedef unsigned long long u64;

// ---------------- K1a: coarse histogram on bits[31:20], LDS-privatized ----------------
__global__ void k_hist1(const float2* __restrict__ scores2, int N,
                        u32* __restrict__ hist) {
    int b = blockIdx.y;
    __shared__ u32 h[NBUCKET];
    for (int t = threadIdx.x; t < NBUCKET; t += blockDim.x) h[t] = 0;
    __syncthreads();
    for (int i = blockIdx.x * blockDim.x + threadIdx.x; i < N; i += gridDim.x * blockDim.x) {
        u32 bits = __float_as_uint(scores2[(size_t)b * N + i].y);
        atomicAdd(&h[bits >> 20], 1u);
    }
    __syncthreads();
    for (int t = threadIdx.x; t < NBUCKET; t += blockDim.x) {
        u32 v = h[t];
        if (v) atomicAdd(&hist[b * NBUCKET + t], v);
    }
}

// ---------------- K2a: coarse threshold bucket t1 + count strictly above ----------------
__global__ void k_thresh1(const u32* __restrict__ hist, u32* __restrict__ t1,
                          u32* __restrict__ above1) {
    int b = blockIdx.x;
    __shared__ u32 h[NBUCKET];
    __shared__ u32 part[256];
    for (int t = threadIdx.x; t < NBUCKET; t += blockDim.x) h[t] = hist[b * NBUCKET + t];
    __syncthreads();
    if (threadIdx.x < 256) {
        u32 s = 0;
        for (int j = 0; j < 16; ++j) s += h[threadIdx.x * 16 + j];
        part[threadIdx.x] = s;
    }
    __syncthreads();
    if (threadIdx.x == 0) {
        u32 acc = 0;
        int c;
        for (c = 255; c >= 0; --c) {
            if (acc + part[c] >= PRE_NMS) break;
            acc += part[c];
        }
        int t;
        for (t = c * 16 + 15; ; --t) {
            if (acc + h[t] >= PRE_NMS) break;
            acc += h[t];
        }
        t1[b] = (u32)t;
        above1[b] = acc;     // count with bucket strictly greater than t
    }
}

// ---------------- K1b: fine histogram of bucket-t1 elements on bits[19:8] ----------------
__global__ void k_hist2(const float2* __restrict__ scores2, int N,
                        const u32* __restrict__ t1, u32* __restrict__ hist2) {
    int b = blockIdx.y;
    u32 t1v = t1[b];
    __shared__ u32 h[NBUCKET];
    for (int t = threadIdx.x; t < NBUCKET; t += blockDim.x) h[t] = 0;
    __syncthreads();
    for (int i = blockIdx.x * blockDim.x + threadIdx.x; i < N; i += gridDim.x * blockDim.x) {
        u32 bits = __float_as_uint(scores2[(size_t)b * N + i].y);
        if ((bits >> 20) == t1v)
            atomicAdd(&h[(bits >> 8) & 0xFFFu], 1u);
    }
    __syncthreads();
    for (int t = threadIdx.x; t < NBUCKET; t += blockDim.x) {
        u32 v = h[t];
        if (v) atomicAdd(&hist2[b * NBUCKET + t], v);
    }
}

// ---------------- K2b: fine threshold t2 within bucket t1 ----------------
__global__ void k_thresh2(const u32* __restrict__ hist2, const u32* __restrict__ above1,
                          u32* __restrict__ t2) {
    int b = blockIdx.x;
    __shared__ u32 h[NBUCKET];
    __shared__ u32 part[256];
    for (int t = threadIdx.x; t < NBUCKET; t += blockDim.x) h[t] = hist2[b * NBUCKET + t];
    __syncthreads();
    if (threadIdx.x < 256) {
        u32 s = 0;
        for (int j = 0; j < 16; ++j) s += h[threadIdx.x * 16 + j];
        part[threadIdx.x] = s;
    }
    __syncthreads();
    if (threadIdx.x == 0) {
        u32 need = PRE_NMS - above1[b];   // >0 by construction of t1
        u32 acc = 0;
        int c;
        for (c = 255; c >= 0; --c) {
            if (acc + part[c] >= need) break;
            acc += part[c];
        }
        int t;
        for (t = c * 16 + 15; ; --t) {
            if (acc + h[t] >= need) break;
            acc += h[t];
        }
        t2[b] = (u32)t;
    }
}

// ---------------- K3: gather candidate keys (block-aggregated atomic) ----------------
__global__ void k_gather(const float2* __restrict__ scores2, int N,
                         const u32* __restrict__ t1, const u32* __restrict__ t2,
                         u32* __restrict__ cnt, u64* __restrict__ keys) {
    int b = blockIdx.y;
    int i = blockIdx.x * blockDim.x + threadIdx.x;
    int lane = threadIdx.x & 63, wave = threadIdx.x >> 6;
    __shared__ u32 wcnts[4];
    __shared__ u32 wbase[4];
    u32 bits = 0;
    bool take = false;
    if (i < N) {
        bits = __float_as_uint(scores2[(size_t)b * N + i].y);
        u32 bk = bits >> 20;
        u32 t1v = t1[b];
        take = (bk > t1v) || (bk == t1v && ((bits >> 8) & 0xFFFu) >= t2[b]);
    }
    u64 ball = __ballot(take);
    if (lane == 0) wcnts[wave] = (u32)__popcll(ball);
    __syncthreads();
    if (threadIdx.x == 0) {
        u32 tot = wcnts[0] + wcnts[1] + wcnts[2] + wcnts[3];
        u32 base = tot ? atomicAdd(&cnt[b], tot) : 0u;
        u32 acc = base;
        for (int w = 0; w < 4; ++w) { wbase[w] = acc; acc += wcnts[w]; }
    }
    __syncthreads();
    if (take) {
        u32 pos = wbase[wave] + (u32)__popcll(ball & ((1ull << lane) - 1ull));
        if (pos < CAP)
            keys[(size_t)b * CAP + pos] = ((u64)bits << 32) | (u32)(~i);
    }
}

// ---------------- K4: bitonic sort 8192 keys, write top-6000 indices ----------------
__global__ __launch_bounds__(1024) void k_sort(const u64* __restrict__ keys,
                                               const u32* __restrict__ cnt,
                                               u32* __restrict__ sel) {
    int b = blockIdx.x;
    __shared__ u64 a[CAP];
    u32 c = cnt[b];
    if (c > CAP) c = CAP;
    for (int t = threadIdx.x; t < CAP; t += 1024)
        a[t] = (t < (int)c) ? keys[(size_t)b * CAP + t] : 0ull;
    __syncthreads();
    for (int k = 2; k <= CAP; k <<= 1) {
        for (int j = k >> 1; j > 0; j >>= 1) {
            for (int t = threadIdx.x; t < CAP / 2; t += 1024) {
                int i = ((t & ~(j - 1)) << 1) | (t & (j - 1));
                int p = i | j;
                u64 x = a[i], y = a[p];
                bool up = (i & k) == 0;
                bool sw = up ? (x < y) : (x > y);   // descending sort
                if (sw) { a[i] = y; a[p] = x; }
            }
            __syncthreads();
        }
    }
    for (int r = threadIdx.x; r < PRE_NMS; r += 1024)
        sel[b * PRE_NMS + r] = ~(u32)(a[r]);
}

// ---------------- K5: decode + clip selected boxes (left & right) ----------------
__global__ void k_decode(const float* __restrict__ deltas, const float* __restrict__ anchors,
                         const float* __restrict__ im_info, const u32* __restrict__ sel,
                         int N, int total, float* __restrict__ boxes) {
#pragma clang fp contract(off)
    int idx = blockIdx.x * blockDim.x + threadIdx.x;
    if (idx >= total) return;
    int b = idx / PRE_NMS;
    int r = idx - b * PRE_NMS;
    u32 i = sel[idx];
    float4 a = ((const float4*)anchors)[i];
    const float* d = deltas + ((size_t)b * N + i) * 6;
    float d0 = d[0], d1 = d[1], d2 = d[2], d3 = d[3], d4 = d[4], d5 = d[5];
    float w  = a.z - a.x + 1.0f;
    float h  = a.w - a.y + 1.0f;
    float cx = a.x + 0.5f * w;
    float cy = a.y + 0.5f * h;
    float Hm1 = im_info[b * 3 + 0] - 1.0f;
    float Wm1 = im_info[b * 3 + 1] - 1.0f;

    // correctly-rounded f32 exp via double (matches numpy's near-CR f32 exp)
    float e3 = (float)exp((double)d3);
    float e2 = (float)exp((double)d2);
    float e5 = (float)exp((double)d5);

    float pcy = d1 * h + cy;
    float ph  = e3 * h;
    float y1 = fminf(fmaxf(pcy - 0.5f * ph, 0.0f), Hm1);
    float y2 = fminf(fmaxf(pcy + 0.5f * ph, 0.0f), Hm1);

    {   // left: dx=d0, dw=d2
        float pcx = d0 * w + cx;
        float pw  = e2 * w;
        float x1 = fminf(fmaxf(pcx - 0.5f * pw, 0.0f), Wm1);
        float x2 = fminf(fmaxf(pcx + 0.5f * pw, 0.0f), Wm1);
        float* o = boxes + ((size_t)(b * 2 + 0) * PRE_NMS + r) * 4;
        o[0] = x1; o[1] = y1; o[2] = x2; o[3] = y2;
    }
    {   // right: dx=d4, dw=d5
        float pcx = d4 * w + cx;
        float pw  = e5 * w;
        float x1 = fminf(fmaxf(pcx - 0.5f * pw, 0.0f), Wm1);
        float x2 = fminf(fmaxf(pcx + 0.5f * pw, 0.0f), Wm1);
        float* o = boxes + ((size_t)(b * 2 + 1) * PRE_NMS + r) * 4;
        o[0] = x1; o[1] = y1; o[2] = x2; o[3] = y2;
    }
}

// ---------------- K6: pairwise IoU bitmask, row-major m[row][w] (upper triangle) --------
__global__ void k_mask(const float* __restrict__ boxes, u64* __restrict__ masks) {
#pragma clang fp contract(off)
    int z = blockIdx.z;
    const float* bx = boxes + (size_t)z * PRE_NMS * 4;
    u64* m = masks + (size_t)z * PRE_NMS * NMS_W;
    int rowStart = blockIdx.y * 64;
    int colStart = blockIdx.x * 64;
    int row = rowStart + threadIdx.x;
    if (blockIdx.x < blockIdx.y) {           // all cols < row: zero word
        if (row < PRE_NMS) m[(size_t)row * NMS_W + blockIdx.x] = 0ull;
        return;
    }
    __shared__ float4 cb[64];
    int col0 = colStart + threadIdx.x;
    cb[threadIdx.x] = (col0 < PRE_NMS) ? ((const float4*)bx)[col0] : make_float4(0.f, 0.f, 0.f, 0.f);
    __syncthreads();
    if (row >= PRE_NMS) return;
    float4 rb = ((const float4*)bx)[row];
    float rA = (rb.z - rb.x + 1.0f) * (rb.w - rb.y + 1.0f);
    u64 word = 0;
    #pragma unroll 4
    for (int c = 0; c < 64; ++c) {
        int col = colStart + c;
        if (col <= row || col >= PRE_NMS) continue;
        float4 q = cb[c];
        float xx1 = fmaxf(rb.x, q.x);
        float yy1 = fmaxf(rb.y, q.y);
        float xx2 = fminf(rb.z, q.z);
        float yy2 = fminf(rb.w, q.w);
        float iw = fmaxf(xx2 - xx1 + 1.0f, 0.0f);
        float ih = fmaxf(yy2 - yy1 + 1.0f, 0.0f);
        float inter = iw * ih;
        float qA = (q.z - q.x + 1.0f) * (q.w - q.y + 1.0f);
        float iou = inter / (rA + qA - inter);
        if (iou > NMS_TH) word |= (1ull << c);
    }
    m[(size_t)row * NMS_W + blockIdx.x] = word;
}

// ---------------- K7: joint early-exit tiled greedy scan (1 block / image) ----------------
__global__ __launch_bounds__(512, 1) void k_scan(const u64* __restrict__ masks,
                                                 u64* __restrict__ comb) {
    int img = blockIdx.x;
    const u64* mL = masks + (size_t)(img * 2 + 0) * PRE_NMS * NMS_W;
    const u64* mR = masks + (size_t)(img * 2 + 1) * PRE_NMS * NMS_W;
    __shared__ u32 supL[NMS_W * 2], supR[NMS_W * 2];
    __shared__ u64 ldsKeepL, ldsKeepR;
    __shared__ u32 ldsCnt;
    int tid = threadIdx.x, lane = tid & 63, wave = tid >> 6;
    for (int i = tid; i < NMS_W * 2; i += 512) { supL[i] = 0; supR[i] = 0; }
    if (tid == 0) ldsCnt = 0;
    __syncthreads();

    u32 cnt = 0;
    int t = 0;
    for (; t < NMS_W; ++t) {
        int rows = PRE_NMS - t * 64; if (rows > 64) rows = 64;
        u64 valid = (rows == 64) ? ~0ull : ((1ull << rows) - 1ull);
        // ---- A-phase: wave 0 decides ----
        if (wave == 0) {
            int row = t * 64 + lane;
            u64 dgL = (lane < rows) ? mL[(size_t)row * NMS_W + t] : 0ull;
            u64 dgR = (lane < rows) ? mR[(size_t)row * NMS_W + t] : 0ull;
            u64 curL = ((u64)supL[2 * t + 1] << 32) | supL[2 * t];
            u64 curR = ((u64)supR[2 * t + 1] << 32) | supR[2 * t];
            u64 aliveL = ~curL & valid;
            u64 candL = __ballot(dgL != 0ull) & aliveL;
            while (candL) {
                int f = __ffsll((long long)candL) - 1;
                u64 df = __shfl(dgL, f);        // bits only > f (upper triangle)
                aliveL &= ~df;
                candL &= ~(1ull << f);
                candL &= aliveL;
            }
            u64 aliveR = ~curR & valid;
            u64 candR = __ballot(dgR != 0ull) & aliveR;
            while (candR) {
                int f = __ffsll((long long)candR) - 1;
                u64 df = __shfl(dgR, f);
                aliveR &= ~df;
                candR &= ~(1ull << f);
                candR &= aliveR;
            }
            u64 cw = aliveL & aliveR;
            cnt += (u32)__popcll(cw);
            if (lane == 0) {
                ldsKeepL = aliveL; ldsKeepR = aliveR; ldsCnt = cnt;
                comb[(size_t)img * NMS_W + t] = cw;
            }
        }
        __syncthreads();
        if (ldsCnt >= POST_NMS) { ++t; break; }   // comb[t] already written & counted
        // ---- B-phase: OR kept rows into sup (all waves) ----
        u64 kL = ldsKeepL, kR = ldsKeepR;
        u64 aL0 = 0, aL1 = 0, aR0 = 0, aR1 = 0;
        bool hi = (lane + 64) < NMS_W;
        #pragma unroll
        for (int k = 0; k < 8; ++k) {
            int r = wave + k * 8;
            size_t row = (size_t)(t * 64 + r);
            if ((kL >> r) & 1ull) {               // wave-uniform branch
                aL0 |= mL[row * NMS_W + lane];
                if (hi) aL1 |= mL[row * NMS_W + 64 + lane];
            }
            if ((kR >> r) & 1ull) {
                aR0 |= mR[row * NMS_W + lane];
                if (hi) aR1 |= mR[row * NMS_W + 64 + lane];
            }
        }
        if (aL0) { atomicOr(&supL[2 * lane], (u32)aL0); atomicOr(&supL[2 * lane + 1], (u32)(aL0 >> 32)); }
        if (hi && aL1) { atomicOr(&supL[2 * (lane + 64)], (u32)aL1); atomicOr(&supL[2 * (lane + 64) + 1], (u32)(aL1 >> 32)); }
        if (aR0) { atomicOr(&supR[2 * lane], (u32)aR0); atomicOr(&supR[2 * lane + 1], (u32)(aR0 >> 32)); }
        if (hi && aR1) { atomicOr(&supR[2 * (lane + 64)], (u32)aR1); atomicOr(&supR[2 * (lane + 64) + 1], (u32)(aR1 >> 32)); }
        __syncthreads();
    }
    // zero remaining comb words (ws is re-poisoned 0xAA every call)
    for (int w = t + tid; w < NMS_W; w += 512)
        comb[(size_t)img * NMS_W + w] = 0ull;
}

// ---------------- K8: compact combined keeps, write output ----------------
__global__ void k_final(const u64* __restrict__ combw, const float* __restrict__ boxes,
                        float* __restrict__ out, int B) {
    int b = blockIdx.x;
    __shared__ u64 comb[NMS_W];
    __shared__ u32 pref[NMS_W + 1];
    int t = threadIdx.x;   // block = 128
    if (t < NMS_W) {
        u64 c = combw[(size_t)b * NMS_W + t];
        if (t == NMS_W - 1) c &= (1ull << (PRE_NMS - 64 * (NMS_W - 1))) - 1ull;
        comb[t] = c;
    }
    __syncthreads();
    if (t == 0) {
        u32 acc = 0;
        for (int w = 0; w < NMS_W; ++w) { pref[w] = acc; acc += (u32)__popcll(comb[w]); }
        pref[NMS_W] = acc;
    }
    __syncthreads();
    u32 nk = pref[NMS_W];
    const float* bl = boxes + (size_t)(b * 2 + 0) * PRE_NMS * 4;
    const float* br = boxes + (size_t)(b * 2 + 1) * PRE_NMS * 4;
    float* outL = out + (size_t)b * POST_NMS * 5;
    float* outR = out + (size_t)B * POST_NMS * 5 + (size_t)b * POST_NMS * 5;
    if (t < NMS_W) {
        u64 c = comb[t];
        u32 r = pref[t];
        while (c) {
            int bit = __ffsll((long long)c) - 1;
            c &= c - 1;
            if (r < POST_NMS) {
                int i = t * 64 + bit;
                float4 L = ((const float4*)bl)[i];
                float4 R = ((const float4*)br)[i];
                outL[r * 5 + 0] = (float)b;
                outL[r * 5 + 1] = L.x; outL[r * 5 + 2] = L.y;
                outL[r * 5 + 3] = L.z; outL[r * 5 + 4] = L.w;
                outR[r * 5 + 0] = (float)b;
                outR[r * 5 + 1] = R.x; outR[r * 5 + 2] = R.y;
                outR[r * 5 + 3] = R.z; outR[r * 5 + 4] = R.w;
            }
            ++r;
        }
    }
    for (u32 r = nk + t; r < POST_NMS; r += blockDim.x) {
        outL[r * 5 + 0] = (float)b;
        outL[r * 5 + 1] = 0.f; outL[r * 5 + 2] = 0.f; outL[r * 5 + 3] = 0.f; outL[r * 5 + 4] = 0.f;
        outR[r * 5 + 0] = (float)b;
        outR[r * 5 + 1] = 0.f; outR[r * 5 + 2] = 0.f; outR[r * 5 + 3] = 0.f; outR[r * 5 + 4] = 0.f;
    }
}

extern "C" void kernel_launch(void* const* d_in, const int* in_sizes, int n_in,
                              void* d_out, int out_size, void* d_ws, size_t ws_size,
                              hipStream_t stream) {
    const float* scores  = (const float*)d_in[0];
    const float* deltas  = (const float*)d_in[1];
    const float* im_info = (const float*)d_in[2];
    const float* anchors = (const float*)d_in[3];
    int B = in_sizes[2] / 3;      // 2
    int N = in_sizes[3] / 4;      // 245520

    char* p = (char*)d_ws;
    auto alloc = [&](size_t bytes) -> char* {
        char* r = p;
        p += (bytes + 255) & ~(size_t)255;
        return r;
    };
    u32*  hist1 = (u32*) alloc((size_t)B * NBUCKET * 4);
    u32*  hist2 = (u32*) alloc((size_t)B * NBUCKET * 4);
    u32*  cnt   = (u32*) alloc((size_t)B * 4);
    u32*  t1    = (u32*) alloc((size_t)B * 4);
    u32*  t2    = (u32*) alloc((size_t)B * 4);
    u32*  above1= (u32*) alloc((size_t)B * 4);
    u64*  keys  = (u64*) alloc((size_t)B * CAP * 8);
    u32*  sel   = (u32*) alloc((size_t)B * PRE_NMS * 4);
    float* boxes = (float*)alloc((size_t)B * 2 * PRE_NMS * 4 * 4);
    u64*  comb  = (u64*) alloc((size_t)B * NMS_W * 8);
    u64*  masks = (u64*) alloc((size_t)B * 2 * (size_t)PRE_NMS * NMS_W * 8);

    hipMemsetAsync(hist1, 0, (size_t)B * NBUCKET * 4, stream);
    hipMemsetAsync(hist2, 0, (size_t)B * NBUCKET * 4, stream);
    hipMemsetAsync(cnt,   0, (size_t)B * 4, stream);

    int total = B * N;
    const float2* scores2 = (const float2*)scores;
    dim3 hg(128, B);
    k_hist1  <<<hg, 256, 0, stream>>>(scores2, N, hist1);
    k_thresh1<<<B, 256, 0, stream>>>(hist1, t1, above1);
    k_hist2  <<<hg, 256, 0, stream>>>(scores2, N, t1, hist2);
    k_thresh2<<<B, 256, 0, stream>>>(hist2, above1, t2);
    dim3 gg((N + 255) / 256, B);
    k_gather <<<gg, 256, 0, stream>>>(scores2, N, t1, t2, cnt, keys);
    k_sort   <<<B, 1024, 0, stream>>>(keys, cnt, sel);
    int dt = B * PRE_NMS;
    k_decode <<<(dt + 255) / 256, 256, 0, stream>>>(deltas, anchors, im_info, sel, N, dt, boxes);
    dim3 mg(NMS_W, NMS_W, B * 2);
    k_mask   <<<mg, 64, 0, stream>>>(boxes, masks);
    k_scan   <<<B, 512, 0, stream>>>(masks, comb);
    k_final  <<<B, 128, 0, stream>>>(comb, boxes, (float*)d_out, B);
}